// Round 1
// baseline (594.811 us; speedup 1.0000x reference)
//
#include <hip/hip_runtime.h>
#include <math.h>

#define N_NODES 50000
#define N_EDGES 800000
#define ET (N_EDGES + N_NODES)   // with self-loops
#define FDIM 128
#define HEADS 4
#define HID 32
#define NCLS 8
#define NEG 0.2f
#define EPS_BN 1e-5f

// ---------------- graph prep: histogram + scan + scatter ----------------

__global__ void count_deg(const int* __restrict__ ei, int* __restrict__ cnt) {
    int e = blockIdx.x * blockDim.x + threadIdx.x;
    if (e >= ET) return;
    int d = (e < N_EDGES) ? ei[N_EDGES + e] : (e - N_EDGES);
    atomicAdd(&cnt[d], 1);
}

__global__ void scan_partial(const int* __restrict__ cnt, int* __restrict__ offs,
                             int* __restrict__ bsums) {
    __shared__ int s[256];
    int tid = threadIdx.x;
    int i = blockIdx.x * 256 + tid;
    int v = (i < N_NODES) ? cnt[i] : 0;
    s[tid] = v;
    __syncthreads();
    for (int off = 1; off < 256; off <<= 1) {
        int x = (tid >= off) ? s[tid - off] : 0;
        __syncthreads();
        s[tid] += x;
        __syncthreads();
    }
    if (i < N_NODES) offs[i] = s[tid] - v;      // exclusive, block-local
    if (tid == 255) bsums[blockIdx.x] = s[255];
}

__global__ void scan_root(const int* __restrict__ bsums, int* __restrict__ boffs, int nb) {
    __shared__ int s[256];
    int tid = threadIdx.x;
    int v = (tid < nb) ? bsums[tid] : 0;
    s[tid] = v;
    __syncthreads();
    for (int off = 1; off < 256; off <<= 1) {
        int x = (tid >= off) ? s[tid - off] : 0;
        __syncthreads();
        s[tid] += x;
        __syncthreads();
    }
    boffs[tid] = s[tid] - v;                    // exclusive
}

__global__ void scan_add(int* __restrict__ offs, const int* __restrict__ boffs,
                         const int* __restrict__ bsums, int* __restrict__ cursor, int nb) {
    int i = blockIdx.x * 256 + threadIdx.x;
    if (i < N_NODES) {
        int v = offs[i] + boffs[blockIdx.x];
        offs[i] = v;
        cursor[i] = v;
    }
    if (i == 0) offs[N_NODES] = boffs[nb - 1] + bsums[nb - 1];  // == ET
}

__global__ void scatter_edges(const int* __restrict__ ei, int* __restrict__ cursor,
                              int* __restrict__ ssrc) {
    int e = blockIdx.x * blockDim.x + threadIdx.x;
    if (e >= ET) return;
    int s, d;
    if (e < N_EDGES) { s = ei[e]; d = ei[N_EDGES + e]; }
    else             { s = d = e - N_EDGES; }
    int pos = atomicAdd(&cursor[d], 1);
    ssrc[pos] = s;
}

// ---------------- fp32 GEMM: C[M,128] = A[M,128] @ B[128,128] ----------------

#define TM 64
__global__ __launch_bounds__(256) void gemm128(const float* __restrict__ A,
                                               const float* __restrict__ B,
                                               float* __restrict__ C, int M) {
    __shared__ float sA[TM][64];    // 16 KB (half-K tile)
    __shared__ float sB[64][128];   // 32 KB
    int tid = threadIdx.x;
    int rowBase = blockIdx.x * TM;
    int cx = tid & 31;   // col group: cols cx*4 .. cx*4+3
    int ry = tid >> 5;   // 0..7 ; rows ry + 8*i
    float4 acc[8];
    #pragma unroll
    for (int i = 0; i < 8; i++) acc[i] = make_float4(0.f, 0.f, 0.f, 0.f);

    for (int kb = 0; kb < 128; kb += 64) {
        #pragma unroll
        for (int j = 0; j < 4; j++) {           // sA: 64x64 = 1024 float4
            int idx = tid + j * 256;
            int r = idx >> 4, c4 = idx & 15;
            int row = rowBase + r;
            float4 v = make_float4(0.f, 0.f, 0.f, 0.f);
            if (row < M) v = *(const float4*)(A + row * 128 + kb + c4 * 4);
            *(float4*)(&sA[r][c4 * 4]) = v;
        }
        #pragma unroll
        for (int j = 0; j < 8; j++) {           // sB: 64x128 = 2048 float4
            int idx = tid + j * 256;
            int r = idx >> 5, c4 = idx & 31;
            *(float4*)(&sB[r][c4 * 4]) = *(const float4*)(B + (kb + r) * 128 + c4 * 4);
        }
        __syncthreads();
        for (int k = 0; k < 64; k++) {
            float4 b = *(const float4*)(&sB[k][cx * 4]);
            #pragma unroll
            for (int i = 0; i < 8; i++) {
                float a = sA[ry + i * 8][k];
                acc[i].x += a * b.x; acc[i].y += a * b.y;
                acc[i].z += a * b.z; acc[i].w += a * b.w;
            }
        }
        __syncthreads();
    }
    #pragma unroll
    for (int i = 0; i < 8; i++) {
        int row = rowBase + ry + i * 8;
        if (row < M) *(float4*)(C + row * 128 + cx * 4) = acc[i];
    }
}

// ---------------- attention coefficients: a_s/a_d per (node, head) ----------------

__global__ void attn_coeff(const float* __restrict__ h, const float* __restrict__ att_s,
                           const float* __restrict__ att_d,
                           float* __restrict__ asn, float* __restrict__ adn) {
    int t = blockIdx.x * blockDim.x + threadIdx.x;
    if (t >= N_NODES * HEADS) return;
    int node = t >> 2, hd = t & 3;
    const float4* hp = (const float4*)(h + node * 128 + hd * 32);
    const float4* sp = (const float4*)(att_s + hd * 32);
    const float4* dp = (const float4*)(att_d + hd * 32);
    float ps = 0.f, pd = 0.f;
    #pragma unroll
    for (int j = 0; j < 8; j++) {
        float4 hv = hp[j], sv = sp[j], dv = dp[j];
        ps += hv.x * sv.x + hv.y * sv.y + hv.z * sv.z + hv.w * sv.w;
        pd += hv.x * dv.x + hv.y * dv.y + hv.z * dv.z + hv.w * dv.w;
    }
    asn[t] = ps;
    adn[t] = pd;
}

// ---------------- aggregation + bias + BN + ELU (layers 0,1): one wave per node ----

__global__ __launch_bounds__(256) void aggregate(
        const float* __restrict__ h, const float* __restrict__ asn,
        const float* __restrict__ adn, const int* __restrict__ offs,
        const int* __restrict__ ssrc, const float* __restrict__ bias,
        const float* __restrict__ gamma, const float* __restrict__ beta,
        const float* __restrict__ rmean, const float* __restrict__ rvar,
        float* __restrict__ out) {
    int node = blockIdx.x * 4 + (threadIdx.x >> 6);
    if (node >= N_NODES) return;
    int lane = threadIdx.x & 63;
    int c0 = lane << 1;          // 2 channels per lane
    int hd = lane >> 4;          // 16 lanes per head
    float adv = adn[node * 4 + hd];
    int beg = offs[node], end = offs[node + 1];

    float m = -1e30f;
    for (int i = beg; i < end; i++) {
        float e = asn[ssrc[i] * 4 + hd] + adv;
        e = (e > 0.f) ? e : NEG * e;
        m = fmaxf(m, e);
    }
    float den = 0.f, a0 = 0.f, a1 = 0.f;
    for (int i = beg; i < end; i++) {
        int s = ssrc[i];
        float e = asn[s * 4 + hd] + adv;
        e = (e > 0.f) ? e : NEG * e;
        float w = __expf(e - m);
        den += w;
        float2 hv = *(const float2*)(h + s * 128 + c0);
        a0 += w * hv.x;
        a1 += w * hv.y;
    }
    float inv = 1.f / (den + 1e-16f);
    float o0 = a0 * inv + bias[c0];
    float o1 = a1 * inv + bias[c0 + 1];
    o0 = (o0 - rmean[c0])     * rsqrtf(rvar[c0]     + EPS_BN) * gamma[c0]     + beta[c0];
    o1 = (o1 - rmean[c0 + 1]) * rsqrtf(rvar[c0 + 1] + EPS_BN) * gamma[c0 + 1] + beta[c0 + 1];
    o0 = (o0 > 0.f) ? o0 : expm1f(o0);
    o1 = (o1 > 0.f) ? o1 : expm1f(o1);
    *(float2*)(out + node * 128 + c0) = make_float2(o0, o1);
}

// ---------------- layer 2: fused GEMM(128->8) + attn coeffs ----------------

__global__ __launch_bounds__(256) void gemm2_fused(
        const float* __restrict__ x, const float* __restrict__ W2,
        const float* __restrict__ as2, const float* __restrict__ ad2,
        float* __restrict__ h2, float* __restrict__ asn, float* __restrict__ adn) {
    __shared__ float sW[128 * 8];
    __shared__ float sas[8], sad[8];
    int tid = threadIdx.x;
    for (int i = tid; i < 1024; i += 256) sW[i] = W2[i];
    if (tid < 8) { sas[tid] = as2[tid]; sad[tid] = ad2[tid]; }
    __syncthreads();
    int node = blockIdx.x * 256 + tid;
    if (node >= N_NODES) return;
    const float4* xr = (const float4*)(x + node * 128);
    float acc[8];
    #pragma unroll
    for (int c = 0; c < 8; c++) acc[c] = 0.f;
    for (int k4 = 0; k4 < 32; k4++) {
        float4 xv = xr[k4];
        int kb = k4 * 4;
        #pragma unroll
        for (int c = 0; c < 8; c++) {
            acc[c] += xv.x * sW[(kb + 0) * 8 + c];
            acc[c] += xv.y * sW[(kb + 1) * 8 + c];
            acc[c] += xv.z * sW[(kb + 2) * 8 + c];
            acc[c] += xv.w * sW[(kb + 3) * 8 + c];
        }
    }
    float ps = 0.f, pd = 0.f;
    #pragma unroll
    for (int c = 0; c < 8; c++) {
        h2[node * 8 + c] = acc[c];
        ps += acc[c] * sas[c];
        pd += acc[c] * sad[c];
    }
    asn[node] = ps;
    adn[node] = pd;
}

// ---------------- layer 2 aggregation + bias + log_softmax ----------------

__global__ __launch_bounds__(256) void aggregate2(
        const float* __restrict__ h2, const float* __restrict__ asn,
        const float* __restrict__ adn, const int* __restrict__ offs,
        const int* __restrict__ ssrc, const float* __restrict__ b2,
        float* __restrict__ out) {
    int t = blockIdx.x * blockDim.x + threadIdx.x;
    int node = t >> 3, ch = t & 7;
    if (node >= N_NODES) return;
    float adv = adn[node];
    int beg = offs[node], end = offs[node + 1];
    float m = -1e30f;
    for (int i = beg; i < end; i++) {
        float e = asn[ssrc[i]] + adv;
        e = (e > 0.f) ? e : NEG * e;
        m = fmaxf(m, e);
    }
    float den = 0.f, acc = 0.f;
    for (int i = beg; i < end; i++) {
        int s = ssrc[i];
        float e = asn[s] + adv;
        e = (e > 0.f) ? e : NEG * e;
        float w = __expf(e - m);
        den += w;
        acc += w * h2[s * 8 + ch];
    }
    float o = acc / (den + 1e-16f) + b2[ch];
    // log_softmax over the 8 lanes of this node
    float mx = o;
    for (int off = 1; off < 8; off <<= 1) mx = fmaxf(mx, __shfl_xor(mx, off, 8));
    float ex = __expf(o - mx);
    float sum = ex;
    for (int off = 1; off < 8; off <<= 1) sum += __shfl_xor(sum, off, 8);
    out[node * 8 + ch] = o - mx - logf(sum);
}

// ---------------- launch ----------------

extern "C" void kernel_launch(void* const* d_in, const int* in_sizes, int n_in,
                              void* d_out, int out_size, void* d_ws, size_t ws_size,
                              hipStream_t stream) {
    const float* x   = (const float*)d_in[0];
    const int*   ei  = (const int*)d_in[1];
    const float* W0  = (const float*)d_in[2];
    const float* as0 = (const float*)d_in[3];
    const float* ad0 = (const float*)d_in[4];
    const float* b0  = (const float*)d_in[5];
    const float* g0  = (const float*)d_in[6];
    const float* bb0 = (const float*)d_in[7];
    const float* rm0 = (const float*)d_in[8];
    const float* rv0 = (const float*)d_in[9];
    const float* W1  = (const float*)d_in[10];
    const float* as1 = (const float*)d_in[11];
    const float* ad1 = (const float*)d_in[12];
    const float* b1  = (const float*)d_in[13];
    const float* g1  = (const float*)d_in[14];
    const float* bb1 = (const float*)d_in[15];
    const float* rm1 = (const float*)d_in[16];
    const float* rv1 = (const float*)d_in[17];
    const float* W2  = (const float*)d_in[18];
    const float* as2 = (const float*)d_in[19];
    const float* ad2 = (const float*)d_in[20];
    const float* b2  = (const float*)d_in[21];
    float* out = (float*)d_out;

    // workspace carve (all 256B-aligned)
    char* w = (char*)d_ws;
    size_t off = 0;
    auto carve = [&](size_t bytes) {
        void* p = w + off;
        off += (bytes + 255) & ~(size_t)255;
        return p;
    };
    float* bufH   = (float*)carve((size_t)N_NODES * 128 * 4);   // 25.6 MB
    float* bufX   = (float*)carve((size_t)N_NODES * 128 * 4);   // 25.6 MB
    int*   cnt    = (int*)carve((size_t)N_NODES * 4);
    int*   offs   = (int*)carve((size_t)(N_NODES + 1) * 4);
    int*   cursor = (int*)carve((size_t)N_NODES * 4);
    int*   bsums  = (int*)carve(1024);
    int*   boffs  = (int*)carve(1024);
    int*   ssrc   = (int*)carve((size_t)ET * 4);                // 3.4 MB
    float* asn    = (float*)carve((size_t)N_NODES * 4 * 4);
    float* adn    = (float*)carve((size_t)N_NODES * 4 * 4);
    float* h2     = (float*)carve((size_t)N_NODES * 8 * 4);
    float* as2n   = (float*)carve((size_t)N_NODES * 4);
    float* ad2n   = (float*)carve((size_t)N_NODES * 4);
    (void)ws_size; (void)in_sizes; (void)n_in; (void)out_size;

    const int NB = (N_NODES + 255) / 256;  // 196

    // graph prep
    hipMemsetAsync(cnt, 0, (size_t)N_NODES * 4, stream);
    count_deg<<<(ET + 255) / 256, 256, 0, stream>>>(ei, cnt);
    scan_partial<<<NB, 256, 0, stream>>>(cnt, offs, bsums);
    scan_root<<<1, 256, 0, stream>>>(bsums, boffs, NB);
    scan_add<<<NB, 256, 0, stream>>>(offs, boffs, bsums, cursor, NB);
    scatter_edges<<<(ET + 255) / 256, 256, 0, stream>>>(ei, cursor, ssrc);

    // layer 0
    gemm128<<<(N_NODES + TM - 1) / TM, 256, 0, stream>>>(x, W0, bufH, N_NODES);
    attn_coeff<<<(N_NODES * 4 + 255) / 256, 256, 0, stream>>>(bufH, as0, ad0, asn, adn);
    aggregate<<<(N_NODES + 3) / 4, 256, 0, stream>>>(bufH, asn, adn, offs, ssrc,
                                                     b0, g0, bb0, rm0, rv0, bufX);
    // layer 1
    gemm128<<<(N_NODES + TM - 1) / TM, 256, 0, stream>>>(bufX, W1, bufH, N_NODES);
    attn_coeff<<<(N_NODES * 4 + 255) / 256, 256, 0, stream>>>(bufH, as1, ad1, asn, adn);
    aggregate<<<(N_NODES + 3) / 4, 256, 0, stream>>>(bufH, asn, adn, offs, ssrc,
                                                     b1, g1, bb1, rm1, rv1, bufX);
    // layer 2
    gemm2_fused<<<(N_NODES + 255) / 256, 256, 0, stream>>>(bufX, W2, as2, ad2, h2, as2n, ad2n);
    aggregate2<<<(N_NODES * 8 + 255) / 256, 256, 0, stream>>>(h2, as2n, ad2n, offs, ssrc, b2, out);
}

// Round 2
// 461.296 us; speedup vs baseline: 1.2894x; 1.2894x over previous
//
#include <hip/hip_runtime.h>
#include <math.h>

#define N_NODES 50000
#define N_EDGES 800000
#define ET (N_EDGES + N_NODES)   // with self-loops
#define FDIM 128
#define HEADS 4
#define HID 32
#define NCLS 8
#define NEG 0.2f
#define EPS_BN 1e-5f

__device__ __forceinline__ float lrelu(float e) { return e > 0.f ? e : NEG * e; }

// ---------------- graph prep: histogram + scan + scatter ----------------

__global__ void count_deg(const int* __restrict__ ei, int* __restrict__ cnt) {
    int e = blockIdx.x * blockDim.x + threadIdx.x;
    if (e >= ET) return;
    int d = (e < N_EDGES) ? ei[N_EDGES + e] : (e - N_EDGES);
    atomicAdd(&cnt[d], 1);
}

__global__ void scan_partial(const int* __restrict__ cnt, int* __restrict__ offs,
                             int* __restrict__ bsums) {
    __shared__ int s[256];
    int tid = threadIdx.x;
    int i = blockIdx.x * 256 + tid;
    int v = (i < N_NODES) ? cnt[i] : 0;
    s[tid] = v;
    __syncthreads();
    for (int off = 1; off < 256; off <<= 1) {
        int x = (tid >= off) ? s[tid - off] : 0;
        __syncthreads();
        s[tid] += x;
        __syncthreads();
    }
    if (i < N_NODES) offs[i] = s[tid] - v;      // exclusive, block-local
    if (tid == 255) bsums[blockIdx.x] = s[255];
}

__global__ void scan_root(const int* __restrict__ bsums, int* __restrict__ boffs, int nb) {
    __shared__ int s[256];
    int tid = threadIdx.x;
    int v = (tid < nb) ? bsums[tid] : 0;
    s[tid] = v;
    __syncthreads();
    for (int off = 1; off < 256; off <<= 1) {
        int x = (tid >= off) ? s[tid - off] : 0;
        __syncthreads();
        s[tid] += x;
        __syncthreads();
    }
    boffs[tid] = s[tid] - v;                    // exclusive
}

__global__ void scan_add(int* __restrict__ offs, const int* __restrict__ boffs,
                         const int* __restrict__ bsums, int* __restrict__ cursor, int nb) {
    int i = blockIdx.x * 256 + threadIdx.x;
    if (i < N_NODES) {
        int v = offs[i] + boffs[blockIdx.x];
        offs[i] = v;
        cursor[i] = v;
    }
    if (i == 0) offs[N_NODES] = boffs[nb - 1] + bsums[nb - 1];  // == ET
}

__global__ void scatter_edges(const int* __restrict__ ei, int* __restrict__ cursor,
                              int* __restrict__ ssrc) {
    int e = blockIdx.x * blockDim.x + threadIdx.x;
    if (e >= ET) return;
    int s, d;
    if (e < N_EDGES) { s = ei[e]; d = ei[N_EDGES + e]; }
    else             { s = d = e - N_EDGES; }
    int pos = atomicAdd(&cursor[d], 1);
    ssrc[pos] = s;
}

// ---------------- fp32 GEMM: C[M,128] = A[M,128] @ B[128,128] ----------------

#define TM 64
__global__ __launch_bounds__(256) void gemm128(const float* __restrict__ A,
                                               const float* __restrict__ B,
                                               float* __restrict__ C, int M) {
    __shared__ float sA[TM][64];    // 16 KB (half-K tile)
    __shared__ float sB[64][128];   // 32 KB
    int tid = threadIdx.x;
    int rowBase = blockIdx.x * TM;
    int cx = tid & 31;   // col group: cols cx*4 .. cx*4+3
    int ry = tid >> 5;   // 0..7 ; rows ry + 8*i
    float4 acc[8];
    #pragma unroll
    for (int i = 0; i < 8; i++) acc[i] = make_float4(0.f, 0.f, 0.f, 0.f);

    for (int kb = 0; kb < 128; kb += 64) {
        #pragma unroll
        for (int j = 0; j < 4; j++) {           // sA: 64x64 = 1024 float4
            int idx = tid + j * 256;
            int r = idx >> 4, c4 = idx & 15;
            int row = rowBase + r;
            float4 v = make_float4(0.f, 0.f, 0.f, 0.f);
            if (row < M) v = *(const float4*)(A + row * 128 + kb + c4 * 4);
            *(float4*)(&sA[r][c4 * 4]) = v;
        }
        #pragma unroll
        for (int j = 0; j < 8; j++) {           // sB: 64x128 = 2048 float4
            int idx = tid + j * 256;
            int r = idx >> 5, c4 = idx & 31;
            *(float4*)(&sB[r][c4 * 4]) = *(const float4*)(B + (kb + r) * 128 + c4 * 4);
        }
        __syncthreads();
        for (int k = 0; k < 64; k++) {
            float4 b = *(const float4*)(&sB[k][cx * 4]);
            #pragma unroll
            for (int i = 0; i < 8; i++) {
                float a = sA[ry + i * 8][k];
                acc[i].x += a * b.x; acc[i].y += a * b.y;
                acc[i].z += a * b.z; acc[i].w += a * b.w;
            }
        }
        __syncthreads();
    }
    #pragma unroll
    for (int i = 0; i < 8; i++) {
        int row = rowBase + ry + i * 8;
        if (row < M) *(float4*)(C + row * 128 + cx * 4) = acc[i];
    }
}

// ---------------- attention coefficients: a_s/a_d per (node, head) ----------------

__global__ void attn_coeff(const float* __restrict__ h, const float* __restrict__ att_s,
                           const float* __restrict__ att_d,
                           float* __restrict__ asn, float* __restrict__ adn) {
    int t = blockIdx.x * blockDim.x + threadIdx.x;
    if (t >= N_NODES * HEADS) return;
    int node = t >> 2, hd = t & 3;
    const float4* hp = (const float4*)(h + node * 128 + hd * 32);
    const float4* sp = (const float4*)(att_s + hd * 32);
    const float4* dp = (const float4*)(att_d + hd * 32);
    float ps = 0.f, pd = 0.f;
    #pragma unroll
    for (int j = 0; j < 8; j++) {
        float4 hv = hp[j], sv = sp[j], dv = dp[j];
        ps += hv.x * sv.x + hv.y * sv.y + hv.z * sv.z + hv.w * sv.w;
        pd += hv.x * dv.x + hv.y * dv.y + hv.z * dv.z + hv.w * dv.w;
    }
    asn[t] = ps;
    adn[t] = pd;
}

// ------- aggregation + bias + BN + ELU (layers 0,1): one wave per node, edge-parallel -------
// Sweeps 1&2 are edge-parallel over lanes (float4 asn gather covers all 4 heads).
// Phase C: 4 edges in parallel (16 lanes/edge, 8 ch/lane), reduced via shfl_xor 16/32.

__global__ __launch_bounds__(256) void aggregate(
        const float* __restrict__ h, const float* __restrict__ asn,
        const float* __restrict__ adn, const int* __restrict__ offs,
        const int* __restrict__ ssrc, const float* __restrict__ bias,
        const float* __restrict__ gamma, const float* __restrict__ beta,
        const float* __restrict__ rmean, const float* __restrict__ rvar,
        float* __restrict__ out) {
    __shared__ int   sSrc[4][64];
    __shared__ float sW[4][64 * 4];
    int wv = threadIdx.x >> 6;
    int node = blockIdx.x * 4 + wv;
    if (node >= N_NODES) return;
    int lane = threadIdx.x & 63;
    int g  = lane >> 4;     // edge group in phase C (0..3)
    int il = lane & 15;     // channels il*8..il*8+7, head = il>>2
    int beg = offs[node], end = offs[node + 1];
    int deg = end - beg;
    float4 ad4 = *(const float4*)(adn + node * 4);

    // sweep 1: per-head max, edge-parallel
    float4 m4 = make_float4(-1e30f, -1e30f, -1e30f, -1e30f);
    for (int base = 0; base < deg; base += 64) {
        int j = base + lane;
        if (j < deg) {
            int s = ssrc[beg + j];
            float4 a = *(const float4*)(asn + s * 4);
            m4.x = fmaxf(m4.x, lrelu(a.x + ad4.x));
            m4.y = fmaxf(m4.y, lrelu(a.y + ad4.y));
            m4.z = fmaxf(m4.z, lrelu(a.z + ad4.z));
            m4.w = fmaxf(m4.w, lrelu(a.w + ad4.w));
        }
    }
    #pragma unroll
    for (int off = 32; off; off >>= 1) {
        m4.x = fmaxf(m4.x, __shfl_xor(m4.x, off));
        m4.y = fmaxf(m4.y, __shfl_xor(m4.y, off));
        m4.z = fmaxf(m4.z, __shfl_xor(m4.z, off));
        m4.w = fmaxf(m4.w, __shfl_xor(m4.w, off));
    }

    // sweep 2: weights + accumulate
    float4 den4 = make_float4(0.f, 0.f, 0.f, 0.f);
    float acc[8];
    #pragma unroll
    for (int k = 0; k < 8; k++) acc[k] = 0.f;

    for (int base = 0; base < deg; base += 64) {
        int j = base + lane;
        int s = 0;
        float4 w4 = make_float4(0.f, 0.f, 0.f, 0.f);
        if (j < deg) {
            s = ssrc[beg + j];
            float4 a = *(const float4*)(asn + s * 4);
            w4.x = __expf(lrelu(a.x + ad4.x) - m4.x);
            w4.y = __expf(lrelu(a.y + ad4.y) - m4.y);
            w4.z = __expf(lrelu(a.z + ad4.z) - m4.z);
            w4.w = __expf(lrelu(a.w + ad4.w) - m4.w);
            den4.x += w4.x; den4.y += w4.y; den4.z += w4.z; den4.w += w4.w;
        }
        sSrc[wv][lane] = s;
        *(float4*)(&sW[wv][lane * 4]) = w4;     // wave-private LDS, no barrier needed
        int cnt = deg - base; if (cnt > 64) cnt = 64;
        int iters = (cnt + 3) >> 2;
        for (int i = 0; i < iters; i++) {
            int eidx = i * 4 + g;               // invalid slots have w=0, s=0 -> harmless
            int s_e = sSrc[wv][eidx];
            float w = sW[wv][eidx * 4 + (il >> 2)];
            const float* hp = h + (size_t)s_e * 128 + il * 8;
            float4 h0 = *(const float4*)(hp);
            float4 h1 = *(const float4*)(hp + 4);
            acc[0] += w * h0.x; acc[1] += w * h0.y; acc[2] += w * h0.z; acc[3] += w * h0.w;
            acc[4] += w * h1.x; acc[5] += w * h1.y; acc[6] += w * h1.z; acc[7] += w * h1.w;
        }
    }
    // reduce partial sums across the 4 edge groups
    #pragma unroll
    for (int k = 0; k < 8; k++) {
        acc[k] += __shfl_xor(acc[k], 16);
        acc[k] += __shfl_xor(acc[k], 32);
    }
    // reduce den across the wave
    #pragma unroll
    for (int off = 32; off; off >>= 1) {
        den4.x += __shfl_xor(den4.x, off);
        den4.y += __shfl_xor(den4.y, off);
        den4.z += __shfl_xor(den4.z, off);
        den4.w += __shfl_xor(den4.w, off);
    }
    if (g == 0) {
        int head = il >> 2;
        float den = (head & 2) ? ((head & 1) ? den4.w : den4.z)
                               : ((head & 1) ? den4.y : den4.x);
        float inv = 1.f / (den + 1e-16f);
        int c0 = il * 8;
        float4 bi0 = *(const float4*)(bias + c0),  bi1 = *(const float4*)(bias + c0 + 4);
        float4 gm0 = *(const float4*)(gamma + c0), gm1 = *(const float4*)(gamma + c0 + 4);
        float4 bt0 = *(const float4*)(beta + c0),  bt1 = *(const float4*)(beta + c0 + 4);
        float4 rm0 = *(const float4*)(rmean + c0), rm1 = *(const float4*)(rmean + c0 + 4);
        float4 rv0 = *(const float4*)(rvar + c0),  rv1 = *(const float4*)(rvar + c0 + 4);
        float o[8];
        o[0] = acc[0]*inv + bi0.x; o[1] = acc[1]*inv + bi0.y;
        o[2] = acc[2]*inv + bi0.z; o[3] = acc[3]*inv + bi0.w;
        o[4] = acc[4]*inv + bi1.x; o[5] = acc[5]*inv + bi1.y;
        o[6] = acc[6]*inv + bi1.z; o[7] = acc[7]*inv + bi1.w;
        o[0] = (o[0]-rm0.x)*rsqrtf(rv0.x+EPS_BN)*gm0.x + bt0.x;
        o[1] = (o[1]-rm0.y)*rsqrtf(rv0.y+EPS_BN)*gm0.y + bt0.y;
        o[2] = (o[2]-rm0.z)*rsqrtf(rv0.z+EPS_BN)*gm0.z + bt0.z;
        o[3] = (o[3]-rm0.w)*rsqrtf(rv0.w+EPS_BN)*gm0.w + bt0.w;
        o[4] = (o[4]-rm1.x)*rsqrtf(rv1.x+EPS_BN)*gm1.x + bt1.x;
        o[5] = (o[5]-rm1.y)*rsqrtf(rv1.y+EPS_BN)*gm1.y + bt1.y;
        o[6] = (o[6]-rm1.z)*rsqrtf(rv1.z+EPS_BN)*gm1.z + bt1.z;
        o[7] = (o[7]-rm1.w)*rsqrtf(rv1.w+EPS_BN)*gm1.w + bt1.w;
        #pragma unroll
        for (int k = 0; k < 8; k++) o[k] = (o[k] > 0.f) ? o[k] : expm1f(o[k]);
        float* op = out + (size_t)node * 128 + c0;
        *(float4*)(op)     = make_float4(o[0], o[1], o[2], o[3]);
        *(float4*)(op + 4) = make_float4(o[4], o[5], o[6], o[7]);
    }
}

// ---------------- layer 2: fused GEMM(128->8) + attn coeffs ----------------

__global__ __launch_bounds__(256) void gemm2_fused(
        const float* __restrict__ x, const float* __restrict__ W2,
        const float* __restrict__ as2, const float* __restrict__ ad2,
        float* __restrict__ h2, float* __restrict__ asn, float* __restrict__ adn) {
    __shared__ float sW[128 * 8];
    __shared__ float sas[8], sad[8];
    int tid = threadIdx.x;
    for (int i = tid; i < 1024; i += 256) sW[i] = W2[i];
    if (tid < 8) { sas[tid] = as2[tid]; sad[tid] = ad2[tid]; }
    __syncthreads();
    int node = blockIdx.x * 256 + tid;
    if (node >= N_NODES) return;
    const float4* xr = (const float4*)(x + node * 128);
    float acc[8];
    #pragma unroll
    for (int c = 0; c < 8; c++) acc[c] = 0.f;
    for (int k4 = 0; k4 < 32; k4++) {
        float4 xv = xr[k4];
        int kb = k4 * 4;
        #pragma unroll
        for (int c = 0; c < 8; c++) {
            acc[c] += xv.x * sW[(kb + 0) * 8 + c];
            acc[c] += xv.y * sW[(kb + 1) * 8 + c];
            acc[c] += xv.z * sW[(kb + 2) * 8 + c];
            acc[c] += xv.w * sW[(kb + 3) * 8 + c];
        }
    }
    float ps = 0.f, pd = 0.f;
    #pragma unroll
    for (int c = 0; c < 8; c++) {
        h2[node * 8 + c] = acc[c];
        ps += acc[c] * sas[c];
        pd += acc[c] * sad[c];
    }
    asn[node] = ps;
    adn[node] = pd;
}

// ------- layer 2 aggregation + bias + log_softmax: one wave per node, edge-parallel -------

__global__ __launch_bounds__(256) void aggregate2(
        const float* __restrict__ h2, const float* __restrict__ asn,
        const float* __restrict__ adn, const int* __restrict__ offs,
        const int* __restrict__ ssrc, const float* __restrict__ b2,
        float* __restrict__ out) {
    __shared__ int   sSrc[4][64];
    __shared__ float sW[4][64];
    int wv = threadIdx.x >> 6;
    int node = blockIdx.x * 4 + wv;
    if (node >= N_NODES) return;
    int lane = threadIdx.x & 63;
    int g = lane >> 3, c = lane & 7;   // 8 edge groups x 8 channels
    int beg = offs[node], end = offs[node + 1];
    int deg = end - beg;
    float adv = adn[node];

    float m = -1e30f;
    for (int base = 0; base < deg; base += 64) {
        int j = base + lane;
        if (j < deg) m = fmaxf(m, lrelu(asn[ssrc[beg + j]] + adv));
    }
    #pragma unroll
    for (int off = 32; off; off >>= 1) m = fmaxf(m, __shfl_xor(m, off));

    float den = 0.f, acc = 0.f;
    for (int base = 0; base < deg; base += 64) {
        int j = base + lane;
        int s = 0; float w = 0.f;
        if (j < deg) {
            s = ssrc[beg + j];
            w = __expf(lrelu(asn[s] + adv) - m);
            den += w;
        }
        sSrc[wv][lane] = s;
        sW[wv][lane] = w;
        int cnt = deg - base; if (cnt > 64) cnt = 64;
        int iters = (cnt + 7) >> 3;
        for (int i = 0; i < iters; i++) {
            int eidx = i * 8 + g;
            int s_e = sSrc[wv][eidx];
            float w_e = sW[wv][eidx];
            acc += w_e * h2[(size_t)s_e * 8 + c];
        }
    }
    acc += __shfl_xor(acc, 8); acc += __shfl_xor(acc, 16); acc += __shfl_xor(acc, 32);
    #pragma unroll
    for (int off = 32; off; off >>= 1) den += __shfl_xor(den, off);

    float o = acc / (den + 1e-16f) + b2[c];
    float mx = o;
    mx = fmaxf(mx, __shfl_xor(mx, 1));
    mx = fmaxf(mx, __shfl_xor(mx, 2));
    mx = fmaxf(mx, __shfl_xor(mx, 4));
    float ex = __expf(o - mx);
    float sm = ex;
    sm += __shfl_xor(sm, 1); sm += __shfl_xor(sm, 2); sm += __shfl_xor(sm, 4);
    if (g == 0) out[(size_t)node * 8 + c] = o - mx - logf(sm);
}

// ---------------- launch ----------------

extern "C" void kernel_launch(void* const* d_in, const int* in_sizes, int n_in,
                              void* d_out, int out_size, void* d_ws, size_t ws_size,
                              hipStream_t stream) {
    const float* x   = (const float*)d_in[0];
    const int*   ei  = (const int*)d_in[1];
    const float* W0  = (const float*)d_in[2];
    const float* as0 = (const float*)d_in[3];
    const float* ad0 = (const float*)d_in[4];
    const float* b0  = (const float*)d_in[5];
    const float* g0  = (const float*)d_in[6];
    const float* bb0 = (const float*)d_in[7];
    const float* rm0 = (const float*)d_in[8];
    const float* rv0 = (const float*)d_in[9];
    const float* W1  = (const float*)d_in[10];
    const float* as1 = (const float*)d_in[11];
    const float* ad1 = (const float*)d_in[12];
    const float* b1  = (const float*)d_in[13];
    const float* g1  = (const float*)d_in[14];
    const float* bb1 = (const float*)d_in[15];
    const float* rm1 = (const float*)d_in[16];
    const float* rv1 = (const float*)d_in[17];
    const float* W2  = (const float*)d_in[18];
    const float* as2 = (const float*)d_in[19];
    const float* ad2 = (const float*)d_in[20];
    const float* b2  = (const float*)d_in[21];
    float* out = (float*)d_out;

    char* w = (char*)d_ws;
    size_t off = 0;
    auto carve = [&](size_t bytes) {
        void* p = w + off;
        off += (bytes + 255) & ~(size_t)255;
        return p;
    };
    float* bufH   = (float*)carve((size_t)N_NODES * 128 * 4);
    float* bufX   = (float*)carve((size_t)N_NODES * 128 * 4);
    int*   cnt    = (int*)carve((size_t)N_NODES * 4);
    int*   offs   = (int*)carve((size_t)(N_NODES + 1) * 4);
    int*   cursor = (int*)carve((size_t)N_NODES * 4);
    int*   bsums  = (int*)carve(1024);
    int*   boffs  = (int*)carve(1024);
    int*   ssrc   = (int*)carve((size_t)ET * 4);
    float* asn    = (float*)carve((size_t)N_NODES * 4 * 4);
    float* adn    = (float*)carve((size_t)N_NODES * 4 * 4);
    float* h2     = (float*)carve((size_t)N_NODES * 8 * 4);
    float* as2n   = (float*)carve((size_t)N_NODES * 4);
    float* ad2n   = (float*)carve((size_t)N_NODES * 4);
    (void)ws_size; (void)in_sizes; (void)n_in; (void)out_size;

    const int NB = (N_NODES + 255) / 256;

    hipMemsetAsync(cnt, 0, (size_t)N_NODES * 4, stream);
    count_deg<<<(ET + 255) / 256, 256, 0, stream>>>(ei, cnt);
    scan_partial<<<NB, 256, 0, stream>>>(cnt, offs, bsums);
    scan_root<<<1, 256, 0, stream>>>(bsums, boffs, NB);
    scan_add<<<NB, 256, 0, stream>>>(offs, boffs, bsums, cursor, NB);
    scatter_edges<<<(ET + 255) / 256, 256, 0, stream>>>(ei, cursor, ssrc);

    gemm128<<<(N_NODES + TM - 1) / TM, 256, 0, stream>>>(x, W0, bufH, N_NODES);
    attn_coeff<<<(N_NODES * 4 + 255) / 256, 256, 0, stream>>>(bufH, as0, ad0, asn, adn);
    aggregate<<<(N_NODES + 3) / 4, 256, 0, stream>>>(bufH, asn, adn, offs, ssrc,
                                                     b0, g0, bb0, rm0, rv0, bufX);
    gemm128<<<(N_NODES + TM - 1) / TM, 256, 0, stream>>>(bufX, W1, bufH, N_NODES);
    attn_coeff<<<(N_NODES * 4 + 255) / 256, 256, 0, stream>>>(bufH, as1, ad1, asn, adn);
    aggregate<<<(N_NODES + 3) / 4, 256, 0, stream>>>(bufH, asn, adn, offs, ssrc,
                                                     b1, g1, bb1, rm1, rv1, bufX);
    gemm2_fused<<<(N_NODES + 255) / 256, 256, 0, stream>>>(bufX, W2, as2, ad2, h2, as2n, ad2n);
    aggregate2<<<(N_NODES + 3) / 4, 256, 0, stream>>>(h2, as2n, ad2n, offs, ssrc, b2, out);
}

// Round 3
// 412.591 us; speedup vs baseline: 1.4416x; 1.1180x over previous
//
#include <hip/hip_runtime.h>
#include <math.h>

#define N_NODES 50000
#define N_EDGES 800000
#define ET (N_EDGES + N_NODES)   // with self-loops
#define FDIM 128
#define HEADS 4
#define HID 32
#define NCLS 8
#define NEG 0.2f
#define EPS_BN 1e-5f

typedef __attribute__((ext_vector_type(8))) short short8;
typedef __attribute__((ext_vector_type(4))) float f32x4;

__device__ __forceinline__ float lrelu(float e) { return e > 0.f ? e : NEG * e; }
__device__ __forceinline__ float bflo(unsigned u) { return __uint_as_float(u << 16); }
__device__ __forceinline__ float bfhi(unsigned u) { return __uint_as_float(u & 0xffff0000u); }
__device__ __forceinline__ unsigned f2bf(float f) {           // RNE round to bf16 bits
    unsigned b = __float_as_uint(f);
    return (b + 0x7fffu + ((b >> 16) & 1u)) >> 16;
}

// ---------------- graph prep: histogram + scan + scatter ----------------

__global__ void count_deg(const int* __restrict__ ei, int* __restrict__ cnt) {
    int e = blockIdx.x * blockDim.x + threadIdx.x;
    if (e >= ET) return;
    int d = (e < N_EDGES) ? ei[N_EDGES + e] : (e - N_EDGES);
    atomicAdd(&cnt[d], 1);
}

__global__ void scan_partial(const int* __restrict__ cnt, int* __restrict__ offs,
                             int* __restrict__ bsums) {
    __shared__ int s[256];
    int tid = threadIdx.x;
    int i = blockIdx.x * 256 + tid;
    int v = (i < N_NODES) ? cnt[i] : 0;
    s[tid] = v;
    __syncthreads();
    for (int off = 1; off < 256; off <<= 1) {
        int x = (tid >= off) ? s[tid - off] : 0;
        __syncthreads();
        s[tid] += x;
        __syncthreads();
    }
    if (i < N_NODES) offs[i] = s[tid] - v;
    if (tid == 255) bsums[blockIdx.x] = s[255];
}

__global__ void scan_root(const int* __restrict__ bsums, int* __restrict__ boffs, int nb) {
    __shared__ int s[256];
    int tid = threadIdx.x;
    int v = (tid < nb) ? bsums[tid] : 0;
    s[tid] = v;
    __syncthreads();
    for (int off = 1; off < 256; off <<= 1) {
        int x = (tid >= off) ? s[tid - off] : 0;
        __syncthreads();
        s[tid] += x;
        __syncthreads();
    }
    boffs[tid] = s[tid] - v;
}

__global__ void scan_add(int* __restrict__ offs, const int* __restrict__ boffs,
                         const int* __restrict__ bsums, int* __restrict__ cursor, int nb) {
    int i = blockIdx.x * 256 + threadIdx.x;
    if (i < N_NODES) {
        int v = offs[i] + boffs[blockIdx.x];
        offs[i] = v;
        cursor[i] = v;
    }
    if (i == 0) offs[N_NODES] = boffs[nb - 1] + bsums[nb - 1];
}

__global__ void scatter_edges(const int* __restrict__ ei, int* __restrict__ cursor,
                              int* __restrict__ ssrc) {
    int e = blockIdx.x * blockDim.x + threadIdx.x;
    if (e >= ET) return;
    int s, d;
    if (e < N_EDGES) { s = ei[e]; d = ei[N_EDGES + e]; }
    else             { s = d = e - N_EDGES; }
    int pos = atomicAdd(&cursor[d], 1);
    ssrc[pos] = s;
}

// ---------------- bf16 conversions ----------------

__global__ void cast_bf16(const float* __restrict__ in, unsigned short* __restrict__ outp,
                          int n8) {
    int i = blockIdx.x * blockDim.x + threadIdx.x;
    if (i >= n8) return;
    const float4* p = (const float4*)in + (size_t)i * 2;
    float4 a = p[0], b = p[1];
    uint4 o;
    o.x = f2bf(a.x) | (f2bf(a.y) << 16);
    o.y = f2bf(a.z) | (f2bf(a.w) << 16);
    o.z = f2bf(b.x) | (f2bf(b.y) << 16);
    o.w = f2bf(b.z) | (f2bf(b.w) << 16);
    ((uint4*)outp)[i] = o;
}

// pack W[128][128] into B-fragment order for mfma_f32_16x16x32_bf16:
// Wp[((t*4+kc)*64+lane)*8+j] = bf16( W[kc*32+(lane>>4)*8+j][t*16+(lane&15)] )
__global__ void pack_w(const float* __restrict__ W, unsigned short* __restrict__ Wp) {
    int o = blockIdx.x * 256 + threadIdx.x;   // 0..16383
    int j = o & 7, lane = (o >> 3) & 63, kc = (o >> 9) & 3, t = o >> 11;
    int k = kc * 32 + ((lane >> 4) << 3) + j;
    int n = t * 16 + (lane & 15);
    Wp[o] = (unsigned short)f2bf(W[k * 128 + n]);
}

// ------- fused MFMA GEMM (M x 128 @ 128 x 128) + bf16 h-store + attn coeffs -------
// block = 256 threads = 4 waves; each wave computes 16 rows x 128 cols.

__global__ __launch_bounds__(256) void gemm_attn(
        const unsigned short* __restrict__ Ab, const unsigned short* __restrict__ Wp,
        const float* __restrict__ att_s, const float* __restrict__ att_d,
        unsigned short* __restrict__ Hb, float* __restrict__ asn, float* __restrict__ adn,
        int M) {
    __shared__ float tiles[64 * 132];          // 64 rows x 128 cols, ld=132 (pad)
    int tid = threadIdx.x;
    int wv = tid >> 6, lane = tid & 63;
    int base = blockIdx.x * 64;
    int mrow = base + wv * 16 + (lane & 15);
    if (mrow >= M) mrow = M - 1;               // clamp: loads valid, stores guarded
    int koff = (lane >> 4) * 8;                // 8 contiguous k per lane

    f32x4 acc[8];
    #pragma unroll
    for (int t = 0; t < 8; t++) acc[t] = (f32x4){0.f, 0.f, 0.f, 0.f};

    #pragma unroll
    for (int kc = 0; kc < 4; kc++) {
        short8 a = *(const short8*)(Ab + (size_t)mrow * 128 + kc * 32 + koff);
        #pragma unroll
        for (int t = 0; t < 8; t++) {
            short8 b = *(const short8*)(Wp + (((t * 4 + kc) * 64 + lane) << 3));
            acc[t] = __builtin_amdgcn_mfma_f32_16x16x32_bf16(a, b, acc[t], 0, 0, 0);
        }
    }

    // C/D layout: col = lane&15, row = (lane>>4)*4 + reg
    int rbase = wv * 16 + (lane >> 4) * 4;
    int col = lane & 15;
    #pragma unroll
    for (int t = 0; t < 8; t++)
        #pragma unroll
        for (int r = 0; r < 4; r++)
            tiles[(rbase + r) * 132 + t * 16 + col] = acc[t][r];
    __syncthreads();

    // h store as bf16 (coalesced): 64 rows x 16 col-groups of 8
    #pragma unroll
    for (int it = 0; it < 4; it++) {
        int u = tid + it * 256;
        int rl = u >> 4, cg = u & 15;
        int row = base + rl;
        if (row < M) {
            const float* p = tiles + rl * 132 + cg * 8;
            float4 v0 = *(const float4*)(p);
            float4 v1 = *(const float4*)(p + 4);
            uint4 o;
            o.x = f2bf(v0.x) | (f2bf(v0.y) << 16);
            o.y = f2bf(v0.z) | (f2bf(v0.w) << 16);
            o.z = f2bf(v1.x) | (f2bf(v1.y) << 16);
            o.w = f2bf(v1.z) | (f2bf(v1.w) << 16);
            *(uint4*)(Hb + (size_t)row * 128 + cg * 8) = o;
        }
    }

    // attn coeffs from fp32 tile: thread = (row_l, head)
    {
        int rl = tid >> 2, hd = tid & 3;
        int row = base + rl;
        if (row < M) {
            const float* hrow = tiles + rl * 132 + hd * 32;
            const float* as = att_s + hd * 32;
            const float* ad = att_d + hd * 32;
            float ps = 0.f, pd = 0.f;
            #pragma unroll
            for (int i = 0; i < 8; i++) {
                float4 hv = *(const float4*)(hrow + i * 4);
                float4 sv = *(const float4*)(as + i * 4);
                float4 dv = *(const float4*)(ad + i * 4);
                ps += hv.x * sv.x + hv.y * sv.y + hv.z * sv.z + hv.w * sv.w;
                pd += hv.x * dv.x + hv.y * dv.y + hv.z * dv.z + hv.w * dv.w;
            }
            asn[row * 4 + hd] = ps;
            adn[row * 4 + hd] = pd;
        }
    }
}

// ------- aggregation + bias + BN + ELU (layers 0,1): one wave/node, edge-parallel -------
// h table is bf16 (256 B rows); output written as bf16 for the next GEMM.

__global__ __launch_bounds__(256) void aggregate(
        const unsigned short* __restrict__ hb, const float* __restrict__ asn,
        const float* __restrict__ adn, const int* __restrict__ offs,
        const int* __restrict__ ssrc, const float* __restrict__ bias,
        const float* __restrict__ gamma, const float* __restrict__ beta,
        const float* __restrict__ rmean, const float* __restrict__ rvar,
        unsigned short* __restrict__ outb) {
    __shared__ int   sSrc[4][64];
    __shared__ float sW[4][64 * 4];
    int wv = threadIdx.x >> 6;
    int node = blockIdx.x * 4 + wv;
    if (node >= N_NODES) return;
    int lane = threadIdx.x & 63;
    int g  = lane >> 4;     // edge group (0..3)
    int il = lane & 15;     // channels il*8..il*8+7, head = il>>2
    int beg = offs[node], end = offs[node + 1];
    int deg = end - beg;
    float4 ad4 = *(const float4*)(adn + node * 4);

    float4 m4 = make_float4(-1e30f, -1e30f, -1e30f, -1e30f);
    for (int basee = 0; basee < deg; basee += 64) {
        int j = basee + lane;
        if (j < deg) {
            int s = ssrc[beg + j];
            float4 a = *(const float4*)(asn + s * 4);
            m4.x = fmaxf(m4.x, lrelu(a.x + ad4.x));
            m4.y = fmaxf(m4.y, lrelu(a.y + ad4.y));
            m4.z = fmaxf(m4.z, lrelu(a.z + ad4.z));
            m4.w = fmaxf(m4.w, lrelu(a.w + ad4.w));
        }
    }
    #pragma unroll
    for (int off = 32; off; off >>= 1) {
        m4.x = fmaxf(m4.x, __shfl_xor(m4.x, off));
        m4.y = fmaxf(m4.y, __shfl_xor(m4.y, off));
        m4.z = fmaxf(m4.z, __shfl_xor(m4.z, off));
        m4.w = fmaxf(m4.w, __shfl_xor(m4.w, off));
    }

    float4 den4 = make_float4(0.f, 0.f, 0.f, 0.f);
    float acc[8];
    #pragma unroll
    for (int k = 0; k < 8; k++) acc[k] = 0.f;

    for (int basee = 0; basee < deg; basee += 64) {
        int j = basee + lane;
        int s = 0;
        float4 w4 = make_float4(0.f, 0.f, 0.f, 0.f);
        if (j < deg) {
            s = ssrc[beg + j];
            float4 a = *(const float4*)(asn + s * 4);
            w4.x = __expf(lrelu(a.x + ad4.x) - m4.x);
            w4.y = __expf(lrelu(a.y + ad4.y) - m4.y);
            w4.z = __expf(lrelu(a.z + ad4.z) - m4.z);
            w4.w = __expf(lrelu(a.w + ad4.w) - m4.w);
            den4.x += w4.x; den4.y += w4.y; den4.z += w4.z; den4.w += w4.w;
        }
        sSrc[wv][lane] = s;
        *(float4*)(&sW[wv][lane * 4]) = w4;     // wave-private LDS
        int cnt = deg - basee; if (cnt > 64) cnt = 64;
        int iters = (cnt + 3) >> 2;
        for (int i = 0; i < iters; i++) {
            int eidx = i * 4 + g;
            int s_e = sSrc[wv][eidx];
            float w = sW[wv][eidx * 4 + (il >> 2)];
            uint4 u = *(const uint4*)(hb + (size_t)s_e * 128 + il * 8);
            acc[0] += w * bflo(u.x); acc[1] += w * bfhi(u.x);
            acc[2] += w * bflo(u.y); acc[3] += w * bfhi(u.y);
            acc[4] += w * bflo(u.z); acc[5] += w * bfhi(u.z);
            acc[6] += w * bflo(u.w); acc[7] += w * bfhi(u.w);
        }
    }
    #pragma unroll
    for (int k = 0; k < 8; k++) {
        acc[k] += __shfl_xor(acc[k], 16);
        acc[k] += __shfl_xor(acc[k], 32);
    }
    #pragma unroll
    for (int off = 32; off; off >>= 1) {
        den4.x += __shfl_xor(den4.x, off);
        den4.y += __shfl_xor(den4.y, off);
        den4.z += __shfl_xor(den4.z, off);
        den4.w += __shfl_xor(den4.w, off);
    }
    if (g == 0) {
        int head = il >> 2;
        float den = (head & 2) ? ((head & 1) ? den4.w : den4.z)
                               : ((head & 1) ? den4.y : den4.x);
        float inv = 1.f / (den + 1e-16f);
        int c0 = il * 8;
        float4 bi0 = *(const float4*)(bias + c0),  bi1 = *(const float4*)(bias + c0 + 4);
        float4 gm0 = *(const float4*)(gamma + c0), gm1 = *(const float4*)(gamma + c0 + 4);
        float4 bt0 = *(const float4*)(beta + c0),  bt1 = *(const float4*)(beta + c0 + 4);
        float4 rm0 = *(const float4*)(rmean + c0), rm1 = *(const float4*)(rmean + c0 + 4);
        float4 rv0 = *(const float4*)(rvar + c0),  rv1 = *(const float4*)(rvar + c0 + 4);
        float o[8];
        o[0] = acc[0]*inv + bi0.x; o[1] = acc[1]*inv + bi0.y;
        o[2] = acc[2]*inv + bi0.z; o[3] = acc[3]*inv + bi0.w;
        o[4] = acc[4]*inv + bi1.x; o[5] = acc[5]*inv + bi1.y;
        o[6] = acc[6]*inv + bi1.z; o[7] = acc[7]*inv + bi1.w;
        o[0] = (o[0]-rm0.x)*rsqrtf(rv0.x+EPS_BN)*gm0.x + bt0.x;
        o[1] = (o[1]-rm0.y)*rsqrtf(rv0.y+EPS_BN)*gm0.y + bt0.y;
        o[2] = (o[2]-rm0.z)*rsqrtf(rv0.z+EPS_BN)*gm0.z + bt0.z;
        o[3] = (o[3]-rm0.w)*rsqrtf(rv0.w+EPS_BN)*gm0.w + bt0.w;
        o[4] = (o[4]-rm1.x)*rsqrtf(rv1.x+EPS_BN)*gm1.x + bt1.x;
        o[5] = (o[5]-rm1.y)*rsqrtf(rv1.y+EPS_BN)*gm1.y + bt1.y;
        o[6] = (o[6]-rm1.z)*rsqrtf(rv1.z+EPS_BN)*gm1.z + bt1.z;
        o[7] = (o[7]-rm1.w)*rsqrtf(rv1.w+EPS_BN)*gm1.w + bt1.w;
        #pragma unroll
        for (int k = 0; k < 8; k++) o[k] = (o[k] > 0.f) ? o[k] : expm1f(o[k]);
        uint4 ob;
        ob.x = f2bf(o[0]) | (f2bf(o[1]) << 16);
        ob.y = f2bf(o[2]) | (f2bf(o[3]) << 16);
        ob.z = f2bf(o[4]) | (f2bf(o[5]) << 16);
        ob.w = f2bf(o[6]) | (f2bf(o[7]) << 16);
        *(uint4*)(outb + (size_t)node * 128 + c0) = ob;
    }
}

// ---------------- layer 2: fused GEMM(128->8) + attn coeffs (bf16 input) ----------------

__global__ __launch_bounds__(256) void gemm2_fused(
        const unsigned short* __restrict__ xb, const float* __restrict__ W2,
        const float* __restrict__ as2, const float* __restrict__ ad2,
        float* __restrict__ h2, float* __restrict__ asn, float* __restrict__ adn) {
    __shared__ float sW[128 * 8];
    __shared__ float sas[8], sad[8];
    int tid = threadIdx.x;
    for (int i = tid; i < 1024; i += 256) sW[i] = W2[i];
    if (tid < 8) { sas[tid] = as2[tid]; sad[tid] = ad2[tid]; }
    __syncthreads();
    int node = blockIdx.x * 256 + tid;
    if (node >= N_NODES) return;
    const uint4* xr = (const uint4*)(xb + (size_t)node * 128);
    float acc[8];
    #pragma unroll
    for (int c = 0; c < 8; c++) acc[c] = 0.f;
    for (int k8 = 0; k8 < 16; k8++) {
        uint4 u = xr[k8];
        float f[8] = { bflo(u.x), bfhi(u.x), bflo(u.y), bfhi(u.y),
                       bflo(u.z), bfhi(u.z), bflo(u.w), bfhi(u.w) };
        int kb = k8 * 8;
        #pragma unroll
        for (int q = 0; q < 8; q++)
            #pragma unroll
            for (int c = 0; c < 8; c++)
                acc[c] += f[q] * sW[(kb + q) * 8 + c];
    }
    float ps = 0.f, pd = 0.f;
    #pragma unroll
    for (int c = 0; c < 8; c++) {
        h2[(size_t)node * 8 + c] = acc[c];
        ps += acc[c] * sas[c];
        pd += acc[c] * sad[c];
    }
    asn[node] = ps;
    adn[node] = pd;
}

// ------- layer 2 aggregation + bias + log_softmax: one wave/node, edge-parallel -------

__global__ __launch_bounds__(256) void aggregate2(
        const float* __restrict__ h2, const float* __restrict__ asn,
        const float* __restrict__ adn, const int* __restrict__ offs,
        const int* __restrict__ ssrc, const float* __restrict__ b2,
        float* __restrict__ out) {
    __shared__ int   sSrc[4][64];
    __shared__ float sW[4][64];
    int wv = threadIdx.x >> 6;
    int node = blockIdx.x * 4 + wv;
    if (node >= N_NODES) return;
    int lane = threadIdx.x & 63;
    int g = lane >> 3, c = lane & 7;
    int beg = offs[node], end = offs[node + 1];
    int deg = end - beg;
    float adv = adn[node];

    float m = -1e30f;
    for (int basee = 0; basee < deg; basee += 64) {
        int j = basee + lane;
        if (j < deg) m = fmaxf(m, lrelu(asn[ssrc[beg + j]] + adv));
    }
    #pragma unroll
    for (int off = 32; off; off >>= 1) m = fmaxf(m, __shfl_xor(m, off));

    float den = 0.f, acc = 0.f;
    for (int basee = 0; basee < deg; basee += 64) {
        int j = basee + lane;
        int s = 0; float w = 0.f;
        if (j < deg) {
            s = ssrc[beg + j];
            w = __expf(lrelu(asn[s] + adv) - m);
            den += w;
        }
        sSrc[wv][lane] = s;
        sW[wv][lane] = w;
        int cnt = deg - basee; if (cnt > 64) cnt = 64;
        int iters = (cnt + 7) >> 3;
        for (int i = 0; i < iters; i++) {
            int eidx = i * 8 + g;
            acc += sW[wv][eidx] * h2[(size_t)sSrc[wv][eidx] * 8 + c];
        }
    }
    acc += __shfl_xor(acc, 8); acc += __shfl_xor(acc, 16); acc += __shfl_xor(acc, 32);
    #pragma unroll
    for (int off = 32; off; off >>= 1) den += __shfl_xor(den, off);

    float o = acc / (den + 1e-16f) + b2[c];
    float mx = o;
    mx = fmaxf(mx, __shfl_xor(mx, 1));
    mx = fmaxf(mx, __shfl_xor(mx, 2));
    mx = fmaxf(mx, __shfl_xor(mx, 4));
    float ex = __expf(o - mx);
    float sm = ex;
    sm += __shfl_xor(sm, 1); sm += __shfl_xor(sm, 2); sm += __shfl_xor(sm, 4);
    if (g == 0) out[(size_t)node * 8 + c] = o - mx - logf(sm);
}

// ---------------- launch ----------------

extern "C" void kernel_launch(void* const* d_in, const int* in_sizes, int n_in,
                              void* d_out, int out_size, void* d_ws, size_t ws_size,
                              hipStream_t stream) {
    const float* x   = (const float*)d_in[0];
    const int*   ei  = (const int*)d_in[1];
    const float* W0  = (const float*)d_in[2];
    const float* as0 = (const float*)d_in[3];
    const float* ad0 = (const float*)d_in[4];
    const float* b0  = (const float*)d_in[5];
    const float* g0  = (const float*)d_in[6];
    const float* bb0 = (const float*)d_in[7];
    const float* rm0 = (const float*)d_in[8];
    const float* rv0 = (const float*)d_in[9];
    const float* W1  = (const float*)d_in[10];
    const float* as1 = (const float*)d_in[11];
    const float* ad1 = (const float*)d_in[12];
    const float* b1  = (const float*)d_in[13];
    const float* g1  = (const float*)d_in[14];
    const float* bb1 = (const float*)d_in[15];
    const float* rm1 = (const float*)d_in[16];
    const float* rv1 = (const float*)d_in[17];
    const float* W2  = (const float*)d_in[18];
    const float* as2 = (const float*)d_in[19];
    const float* ad2 = (const float*)d_in[20];
    const float* b2  = (const float*)d_in[21];
    float* out = (float*)d_out;

    char* w = (char*)d_ws;
    size_t off = 0;
    auto carve = [&](size_t bytes) {
        void* p = w + off;
        off += (bytes + 255) & ~(size_t)255;
        return p;
    };
    unsigned short* xb   = (unsigned short*)carve((size_t)N_NODES * 128 * 2);  // 12.8 MB
    unsigned short* Hb   = (unsigned short*)carve((size_t)N_NODES * 128 * 2);  // 12.8 MB
    unsigned short* Xb   = (unsigned short*)carve((size_t)N_NODES * 128 * 2);  // 12.8 MB
    unsigned short* W0p  = (unsigned short*)carve(16384 * 2);
    unsigned short* W1p  = (unsigned short*)carve(16384 * 2);
    int*   cnt    = (int*)carve((size_t)N_NODES * 4);
    int*   offs   = (int*)carve((size_t)(N_NODES + 1) * 4);
    int*   cursor = (int*)carve((size_t)N_NODES * 4);
    int*   bsums  = (int*)carve(1024);
    int*   boffs  = (int*)carve(1024);
    int*   ssrc   = (int*)carve((size_t)ET * 4);
    float* asn    = (float*)carve((size_t)N_NODES * 4 * 4);
    float* adn    = (float*)carve((size_t)N_NODES * 4 * 4);
    float* h2     = (float*)carve((size_t)N_NODES * 8 * 4);
    float* as2n   = (float*)carve((size_t)N_NODES * 4);
    float* ad2n   = (float*)carve((size_t)N_NODES * 4);
    (void)ws_size; (void)in_sizes; (void)n_in; (void)out_size;

    const int NB = (N_NODES + 255) / 256;
    const int GB = (N_NODES + 63) / 64;        // gemm blocks

    // graph prep
    hipMemsetAsync(cnt, 0, (size_t)N_NODES * 4, stream);
    count_deg<<<(ET + 255) / 256, 256, 0, stream>>>(ei, cnt);
    scan_partial<<<NB, 256, 0, stream>>>(cnt, offs, bsums);
    scan_root<<<1, 256, 0, stream>>>(bsums, boffs, NB);
    scan_add<<<NB, 256, 0, stream>>>(offs, boffs, bsums, cursor, NB);
    scatter_edges<<<(ET + 255) / 256, 256, 0, stream>>>(ei, cursor, ssrc);

    // bf16 conversions / weight packing
    cast_bf16<<<(N_NODES * 128 / 8 + 255) / 256, 256, 0, stream>>>(x, xb, N_NODES * 128 / 8);
    pack_w<<<64, 256, 0, stream>>>(W0, W0p);
    pack_w<<<64, 256, 0, stream>>>(W1, W1p);

    // layer 0
    gemm_attn<<<GB, 256, 0, stream>>>(xb, W0p, as0, ad0, Hb, asn, adn, N_NODES);
    aggregate<<<(N_NODES + 3) / 4, 256, 0, stream>>>(Hb, asn, adn, offs, ssrc,
                                                     b0, g0, bb0, rm0, rv0, Xb);
    // layer 1
    gemm_attn<<<GB, 256, 0, stream>>>(Xb, W1p, as1, ad1, Hb, asn, adn, N_NODES);
    aggregate<<<(N_NODES + 3) / 4, 256, 0, stream>>>(Hb, asn, adn, offs, ssrc,
                                                     b1, g1, bb1, rm1, rv1, Xb);
    // layer 2
    gemm2_fused<<<NB, 256, 0, stream>>>(Xb, W2, as2, ad2, h2, as2n, ad2n);
    aggregate2<<<(N_NODES + 3) / 4, 256, 0, stream>>>(h2, as2n, ad2n, offs, ssrc, b2, out);
}

// Round 4
// 386.974 us; speedup vs baseline: 1.5371x; 1.0662x over previous
//
#include <hip/hip_runtime.h>
#include <math.h>

#define N_NODES 50000
#define N_EDGES 800000
#define ET (N_EDGES + N_NODES)   // with self-loops
#define FDIM 128
#define HEADS 4
#define HID 32
#define NCLS 8
#define NEG 0.2f
#define EPS_BN 1e-5f

typedef __attribute__((ext_vector_type(8))) short short8;
typedef __attribute__((ext_vector_type(4))) float f32x4;

__device__ __forceinline__ float lrelu(float e) { return e > 0.f ? e : NEG * e; }
__device__ __forceinline__ float bflo(unsigned u) { return __uint_as_float(u << 16); }
__device__ __forceinline__ float bfhi(unsigned u) { return __uint_as_float(u & 0xffff0000u); }
__device__ __forceinline__ unsigned f2bf(float f) {           // RNE round to bf16 bits
    unsigned b = __float_as_uint(f);
    return (b + 0x7fffu + ((b >> 16) & 1u)) >> 16;
}

// ---------------- graph prep: histogram + scan + scatter ----------------

__global__ void count_deg(const int* __restrict__ ei, int* __restrict__ cnt) {
    int e = blockIdx.x * blockDim.x + threadIdx.x;
    if (e >= ET) return;
    int d = (e < N_EDGES) ? ei[N_EDGES + e] : (e - N_EDGES);
    atomicAdd(&cnt[d], 1);
}

__global__ void scan_partial(const int* __restrict__ cnt, int* __restrict__ offs,
                             int* __restrict__ bsums) {
    __shared__ int s[256];
    int tid = threadIdx.x;
    int i = blockIdx.x * 256 + tid;
    int v = (i < N_NODES) ? cnt[i] : 0;
    s[tid] = v;
    __syncthreads();
    for (int off = 1; off < 256; off <<= 1) {
        int x = (tid >= off) ? s[tid - off] : 0;
        __syncthreads();
        s[tid] += x;
        __syncthreads();
    }
    if (i < N_NODES) offs[i] = s[tid] - v;
    if (tid == 255) bsums[blockIdx.x] = s[255];
}

__global__ void scan_root(const int* __restrict__ bsums, int* __restrict__ boffs, int nb) {
    __shared__ int s[256];
    int tid = threadIdx.x;
    int v = (tid < nb) ? bsums[tid] : 0;
    s[tid] = v;
    __syncthreads();
    for (int off = 1; off < 256; off <<= 1) {
        int x = (tid >= off) ? s[tid - off] : 0;
        __syncthreads();
        s[tid] += x;
        __syncthreads();
    }
    boffs[tid] = s[tid] - v;
}

__global__ void scan_add(int* __restrict__ offs, const int* __restrict__ boffs,
                         const int* __restrict__ bsums, int* __restrict__ cursor, int nb) {
    int i = blockIdx.x * 256 + threadIdx.x;
    if (i < N_NODES) {
        int v = offs[i] + boffs[blockIdx.x];
        offs[i] = v;
        cursor[i] = v;
    }
    if (i == 0) offs[N_NODES] = boffs[nb - 1] + bsums[nb - 1];
}

__global__ void scatter_edges(const int* __restrict__ ei, int* __restrict__ cursor,
                              int* __restrict__ ssrc) {
    int e = blockIdx.x * blockDim.x + threadIdx.x;
    if (e >= ET) return;
    int s, d;
    if (e < N_EDGES) { s = ei[e]; d = ei[N_EDGES + e]; }
    else             { s = d = e - N_EDGES; }
    int pos = atomicAdd(&cursor[d], 1);
    ssrc[pos] = s;
}

// ---------------- fused input prep: x->bf16 cast + W0/W1 fragment packing ----------------
// pack: Wp[((t*4+kc)*64+lane)*8+j] = bf16( W[kc*32+(lane>>4)*8+j][t*16+(lane&15)] )

#define CAST_B 3125   // 50000*128/8/256
#define PACK_B 64     // 16384/256

__global__ void prep_inputs(const float* __restrict__ x, unsigned short* __restrict__ xb,
                            const float* __restrict__ W0, unsigned short* __restrict__ W0p,
                            const float* __restrict__ W1, unsigned short* __restrict__ W1p) {
    int b = blockIdx.x, tid = threadIdx.x;
    if (b < CAST_B) {
        int i = b * 256 + tid;                      // i < 800000
        const float4* p = (const float4*)x + (size_t)i * 2;
        float4 a = p[0], c = p[1];
        uint4 o;
        o.x = f2bf(a.x) | (f2bf(a.y) << 16);
        o.y = f2bf(a.z) | (f2bf(a.w) << 16);
        o.z = f2bf(c.x) | (f2bf(c.y) << 16);
        o.w = f2bf(c.z) | (f2bf(c.w) << 16);
        ((uint4*)xb)[i] = o;
    } else {
        int pb = b - CAST_B;
        const float* W = (pb < PACK_B) ? W0 : W1;
        unsigned short* Wp = (pb < PACK_B) ? W0p : W1p;
        int o = (pb & (PACK_B - 1)) * 256 + tid;    // 0..16383
        int j = o & 7, lane = (o >> 3) & 63, kc = (o >> 9) & 3, t = o >> 11;
        int k = kc * 32 + ((lane >> 4) << 3) + j;
        int n = t * 16 + (lane & 15);
        Wp[o] = (unsigned short)f2bf(W[k * 128 + n]);
    }
}

// ------- fused MFMA GEMM (M x 128 @ 128 x 128) + bf16 h-store + attn coeffs -------

__global__ __launch_bounds__(256) void gemm_attn(
        const unsigned short* __restrict__ Ab, const unsigned short* __restrict__ Wp,
        const float* __restrict__ att_s, const float* __restrict__ att_d,
        unsigned short* __restrict__ Hb, float* __restrict__ asn, float* __restrict__ adn,
        int M) {
    __shared__ float tiles[64 * 132];
    int tid = threadIdx.x;
    int wv = tid >> 6, lane = tid & 63;
    int base = blockIdx.x * 64;
    int mrow = base + wv * 16 + (lane & 15);
    if (mrow >= M) mrow = M - 1;
    int koff = (lane >> 4) * 8;

    f32x4 acc[8];
    #pragma unroll
    for (int t = 0; t < 8; t++) acc[t] = (f32x4){0.f, 0.f, 0.f, 0.f};

    #pragma unroll
    for (int kc = 0; kc < 4; kc++) {
        short8 a = *(const short8*)(Ab + (size_t)mrow * 128 + kc * 32 + koff);
        #pragma unroll
        for (int t = 0; t < 8; t++) {
            short8 b = *(const short8*)(Wp + (((t * 4 + kc) * 64 + lane) << 3));
            acc[t] = __builtin_amdgcn_mfma_f32_16x16x32_bf16(a, b, acc[t], 0, 0, 0);
        }
    }

    int rbase = wv * 16 + (lane >> 4) * 4;
    int col = lane & 15;
    #pragma unroll
    for (int t = 0; t < 8; t++)
        #pragma unroll
        for (int r = 0; r < 4; r++)
            tiles[(rbase + r) * 132 + t * 16 + col] = acc[t][r];
    __syncthreads();

    #pragma unroll
    for (int it = 0; it < 4; it++) {
        int u = tid + it * 256;
        int rl = u >> 4, cg = u & 15;
        int row = base + rl;
        if (row < M) {
            const float* p = tiles + rl * 132 + cg * 8;
            float4 v0 = *(const float4*)(p);
            float4 v1 = *(const float4*)(p + 4);
            uint4 o;
            o.x = f2bf(v0.x) | (f2bf(v0.y) << 16);
            o.y = f2bf(v0.z) | (f2bf(v0.w) << 16);
            o.z = f2bf(v1.x) | (f2bf(v1.y) << 16);
            o.w = f2bf(v1.z) | (f2bf(v1.w) << 16);
            *(uint4*)(Hb + (size_t)row * 128 + cg * 8) = o;
        }
    }

    {
        int rl = tid >> 2, hd = tid & 3;
        int row = base + rl;
        if (row < M) {
            const float* hrow = tiles + rl * 132 + hd * 32;
            const float* as = att_s + hd * 32;
            const float* ad = att_d + hd * 32;
            float ps = 0.f, pd = 0.f;
            #pragma unroll
            for (int i = 0; i < 8; i++) {
                float4 hv = *(const float4*)(hrow + i * 4);
                float4 sv = *(const float4*)(as + i * 4);
                float4 dv = *(const float4*)(ad + i * 4);
                ps += hv.x * sv.x + hv.y * sv.y + hv.z * sv.z + hv.w * sv.w;
                pd += hv.x * dv.x + hv.y * dv.y + hv.z * dv.z + hv.w * dv.w;
            }
            asn[row * 4 + hd] = ps;
            adn[row * 4 + hd] = pd;
        }
    }
}

// ------- aggregation + bias + BN + ELU (layers 0,1): one wave/node -------
// First 64 edges: (src, asn) cached in registers across sweeps (no re-gather).
// Phase C: (src,w) int2 pairs in LDS per head; 8 edges/iter (2 gathers in flight).

__global__ __launch_bounds__(256) void aggregate(
        const unsigned short* __restrict__ hb, const float* __restrict__ asn,
        const float* __restrict__ adn, const int* __restrict__ offs,
        const int* __restrict__ ssrc, const float* __restrict__ bias,
        const float* __restrict__ gamma, const float* __restrict__ beta,
        const float* __restrict__ rmean, const float* __restrict__ rvar,
        unsigned short* __restrict__ outb) {
    __shared__ int2 sPair[4][4][64];     // [wave][head][slot] = (src, w)
    int wv = threadIdx.x >> 6;
    int node = blockIdx.x * 4 + wv;
    if (node >= N_NODES) return;
    int lane = threadIdx.x & 63;
    int g  = lane >> 4;       // phase-C edge group (0..3)
    int il = lane & 15;       // channel octet; head = il>>2
    int hh = il >> 2;
    int beg = offs[node], end = offs[node + 1];
    int deg = end - beg;
    float4 ad4 = *(const float4*)(adn + node * 4);

    // lane-local max; block 0 kept in regs
    int s0 = 0;
    float4 e4 = make_float4(-1e30f, -1e30f, -1e30f, -1e30f);
    if (lane < deg) {
        s0 = ssrc[beg + lane];
        float4 a = *(const float4*)(asn + s0 * 4);
        e4.x = lrelu(a.x + ad4.x); e4.y = lrelu(a.y + ad4.y);
        e4.z = lrelu(a.z + ad4.z); e4.w = lrelu(a.w + ad4.w);
    }
    float4 m4 = e4;
    for (int base = 64; base < deg; base += 64) {   // rare (deg > 64)
        int j = base + lane;
        if (j < deg) {
            int s = ssrc[beg + j];
            float4 a = *(const float4*)(asn + s * 4);
            m4.x = fmaxf(m4.x, lrelu(a.x + ad4.x));
            m4.y = fmaxf(m4.y, lrelu(a.y + ad4.y));
            m4.z = fmaxf(m4.z, lrelu(a.z + ad4.z));
            m4.w = fmaxf(m4.w, lrelu(a.w + ad4.w));
        }
    }
    #pragma unroll
    for (int off = 32; off; off >>= 1) {
        m4.x = fmaxf(m4.x, __shfl_xor(m4.x, off));
        m4.y = fmaxf(m4.y, __shfl_xor(m4.y, off));
        m4.z = fmaxf(m4.z, __shfl_xor(m4.z, off));
        m4.w = fmaxf(m4.w, __shfl_xor(m4.w, off));
    }

    float4 den4 = make_float4(0.f, 0.f, 0.f, 0.f);
    float acc[8];
    #pragma unroll
    for (int k = 0; k < 8; k++) acc[k] = 0.f;

    auto phaseC = [&](int cnt) {
        int nIt = (cnt + 7) >> 3;
        const int2* pp = &sPair[wv][hh][0];
        int choff = il << 3;
        for (int i = 0; i < nIt; i++) {
            int e0 = i * 8 + g;
            int2 p0 = pp[e0];
            int2 p1 = pp[e0 + 4];
            float w0 = __int_as_float(p0.y);
            float w1 = __int_as_float(p1.y);
            uint4 u0 = *(const uint4*)(hb + (((unsigned)p0.x) << 7) + choff);
            uint4 u1 = *(const uint4*)(hb + (((unsigned)p1.x) << 7) + choff);
            acc[0] += w0 * bflo(u0.x); acc[1] += w0 * bfhi(u0.x);
            acc[2] += w0 * bflo(u0.y); acc[3] += w0 * bfhi(u0.y);
            acc[4] += w0 * bflo(u0.z); acc[5] += w0 * bfhi(u0.z);
            acc[6] += w0 * bflo(u0.w); acc[7] += w0 * bfhi(u0.w);
            acc[0] += w1 * bflo(u1.x); acc[1] += w1 * bfhi(u1.x);
            acc[2] += w1 * bflo(u1.y); acc[3] += w1 * bfhi(u1.y);
            acc[4] += w1 * bflo(u1.z); acc[5] += w1 * bfhi(u1.z);
            acc[6] += w1 * bflo(u1.w); acc[7] += w1 * bfhi(u1.w);
        }
    };

    // block 0: weights from registers
    {
        float4 w4 = make_float4(0.f, 0.f, 0.f, 0.f);
        if (lane < deg) {
            w4.x = __expf(e4.x - m4.x); w4.y = __expf(e4.y - m4.y);
            w4.z = __expf(e4.z - m4.z); w4.w = __expf(e4.w - m4.w);
            den4.x += w4.x; den4.y += w4.y; den4.z += w4.z; den4.w += w4.w;
        }
        sPair[wv][0][lane] = make_int2(s0, __float_as_int(w4.x));
        sPair[wv][1][lane] = make_int2(s0, __float_as_int(w4.y));
        sPair[wv][2][lane] = make_int2(s0, __float_as_int(w4.z));
        sPair[wv][3][lane] = make_int2(s0, __float_as_int(w4.w));
        int cnt = deg < 64 ? deg : 64;
        phaseC(cnt);
    }
    // rare extra blocks
    for (int base = 64; base < deg; base += 64) {
        int j = base + lane;
        int s = 0;
        float4 w4 = make_float4(0.f, 0.f, 0.f, 0.f);
        if (j < deg) {
            s = ssrc[beg + j];
            float4 a = *(const float4*)(asn + s * 4);
            w4.x = __expf(lrelu(a.x + ad4.x) - m4.x);
            w4.y = __expf(lrelu(a.y + ad4.y) - m4.y);
            w4.z = __expf(lrelu(a.z + ad4.z) - m4.z);
            w4.w = __expf(lrelu(a.w + ad4.w) - m4.w);
            den4.x += w4.x; den4.y += w4.y; den4.z += w4.z; den4.w += w4.w;
        }
        sPair[wv][0][lane] = make_int2(s, __float_as_int(w4.x));
        sPair[wv][1][lane] = make_int2(s, __float_as_int(w4.y));
        sPair[wv][2][lane] = make_int2(s, __float_as_int(w4.z));
        sPair[wv][3][lane] = make_int2(s, __float_as_int(w4.w));
        int cnt = deg - base; if (cnt > 64) cnt = 64;
        phaseC(cnt);
    }

    #pragma unroll
    for (int k = 0; k < 8; k++) {
        acc[k] += __shfl_xor(acc[k], 16);
        acc[k] += __shfl_xor(acc[k], 32);
    }
    #pragma unroll
    for (int off = 32; off; off >>= 1) {
        den4.x += __shfl_xor(den4.x, off);
        den4.y += __shfl_xor(den4.y, off);
        den4.z += __shfl_xor(den4.z, off);
        den4.w += __shfl_xor(den4.w, off);
    }
    if (g == 0) {
        float den = (hh & 2) ? ((hh & 1) ? den4.w : den4.z)
                             : ((hh & 1) ? den4.y : den4.x);
        float inv = 1.f / (den + 1e-16f);
        int c0 = il * 8;
        float4 bi0 = *(const float4*)(bias + c0),  bi1 = *(const float4*)(bias + c0 + 4);
        float4 gm0 = *(const float4*)(gamma + c0), gm1 = *(const float4*)(gamma + c0 + 4);
        float4 bt0 = *(const float4*)(beta + c0),  bt1 = *(const float4*)(beta + c0 + 4);
        float4 rm0 = *(const float4*)(rmean + c0), rm1 = *(const float4*)(rmean + c0 + 4);
        float4 rv0 = *(const float4*)(rvar + c0),  rv1 = *(const float4*)(rvar + c0 + 4);
        float o[8];
        o[0] = acc[0]*inv + bi0.x; o[1] = acc[1]*inv + bi0.y;
        o[2] = acc[2]*inv + bi0.z; o[3] = acc[3]*inv + bi0.w;
        o[4] = acc[4]*inv + bi1.x; o[5] = acc[5]*inv + bi1.y;
        o[6] = acc[6]*inv + bi1.z; o[7] = acc[7]*inv + bi1.w;
        o[0] = (o[0]-rm0.x)*rsqrtf(rv0.x+EPS_BN)*gm0.x + bt0.x;
        o[1] = (o[1]-rm0.y)*rsqrtf(rv0.y+EPS_BN)*gm0.y + bt0.y;
        o[2] = (o[2]-rm0.z)*rsqrtf(rv0.z+EPS_BN)*gm0.z + bt0.z;
        o[3] = (o[3]-rm0.w)*rsqrtf(rv0.w+EPS_BN)*gm0.w + bt0.w;
        o[4] = (o[4]-rm1.x)*rsqrtf(rv1.x+EPS_BN)*gm1.x + bt1.x;
        o[5] = (o[5]-rm1.y)*rsqrtf(rv1.y+EPS_BN)*gm1.y + bt1.y;
        o[6] = (o[6]-rm1.z)*rsqrtf(rv1.z+EPS_BN)*gm1.z + bt1.z;
        o[7] = (o[7]-rm1.w)*rsqrtf(rv1.w+EPS_BN)*gm1.w + bt1.w;
        #pragma unroll
        for (int k = 0; k < 8; k++) o[k] = (o[k] > 0.f) ? o[k] : expm1f(o[k]);
        uint4 ob;
        ob.x = f2bf(o[0]) | (f2bf(o[1]) << 16);
        ob.y = f2bf(o[2]) | (f2bf(o[3]) << 16);
        ob.z = f2bf(o[4]) | (f2bf(o[5]) << 16);
        ob.w = f2bf(o[6]) | (f2bf(o[7]) << 16);
        *(uint4*)(outb + (size_t)node * 128 + c0) = ob;
    }
}

// ---------------- layer 2: fused GEMM(128->8) + attn coeffs (bf16 input) ----------------

__global__ __launch_bounds__(256) void gemm2_fused(
        const unsigned short* __restrict__ xb, const float* __restrict__ W2,
        const float* __restrict__ as2, const float* __restrict__ ad2,
        float* __restrict__ h2, float* __restrict__ asn, float* __restrict__ adn) {
    __shared__ float sW[128 * 8];
    __shared__ float sas[8], sad[8];
    int tid = threadIdx.x;
    for (int i = tid; i < 1024; i += 256) sW[i] = W2[i];
    if (tid < 8) { sas[tid] = as2[tid]; sad[tid] = ad2[tid]; }
    __syncthreads();
    int node = blockIdx.x * 256 + tid;
    if (node >= N_NODES) return;
    const uint4* xr = (const uint4*)(xb + (size_t)node * 128);
    float acc[8];
    #pragma unroll
    for (int c = 0; c < 8; c++) acc[c] = 0.f;
    for (int k8 = 0; k8 < 16; k8++) {
        uint4 u = xr[k8];
        float f[8] = { bflo(u.x), bfhi(u.x), bflo(u.y), bfhi(u.y),
                       bflo(u.z), bfhi(u.z), bflo(u.w), bfhi(u.w) };
        int kb = k8 * 8;
        #pragma unroll
        for (int q = 0; q < 8; q++)
            #pragma unroll
            for (int c = 0; c < 8; c++)
                acc[c] += f[q] * sW[(kb + q) * 8 + c];
    }
    float ps = 0.f, pd = 0.f;
    #pragma unroll
    for (int c = 0; c < 8; c++) {
        h2[(size_t)node * 8 + c] = acc[c];
        ps += acc[c] * sas[c];
        pd += acc[c] * sad[c];
    }
    asn[node] = ps;
    adn[node] = pd;
}

// ------- layer 2 aggregation + bias + log_softmax: one wave/node -------

__global__ __launch_bounds__(256) void aggregate2(
        const float* __restrict__ h2, const float* __restrict__ asn,
        const float* __restrict__ adn, const int* __restrict__ offs,
        const int* __restrict__ ssrc, const float* __restrict__ b2,
        float* __restrict__ out) {
    __shared__ int2 sPair[4][64];
    int wv = threadIdx.x >> 6;
    int node = blockIdx.x * 4 + wv;
    if (node >= N_NODES) return;
    int lane = threadIdx.x & 63;
    int g = lane >> 3, c = lane & 7;   // 8 edge groups x 8 channels
    int beg = offs[node], end = offs[node + 1];
    int deg = end - beg;
    float adv = adn[node];

    int s0 = 0;
    float e0v = -1e30f;
    if (lane < deg) {
        s0 = ssrc[beg + lane];
        e0v = lrelu(asn[s0] + adv);
    }
    float m = e0v;
    for (int base = 64; base < deg; base += 64) {
        int j = base + lane;
        if (j < deg) m = fmaxf(m, lrelu(asn[ssrc[beg + j]] + adv));
    }
    #pragma unroll
    for (int off = 32; off; off >>= 1) m = fmaxf(m, __shfl_xor(m, off));

    float den = 0.f, acc = 0.f;
    auto phaseC = [&](int cnt) {
        int nIt = (cnt + 15) >> 4;
        const int2* pp = &sPair[wv][0];
        for (int i = 0; i < nIt; i++) {
            int e = i * 16 + g;
            int2 p0 = pp[e];
            int2 p1 = pp[e + 8];
            acc += __int_as_float(p0.y) * h2[(((unsigned)p0.x) << 3) + c];
            acc += __int_as_float(p1.y) * h2[(((unsigned)p1.x) << 3) + c];
        }
    };

    {
        float w = 0.f;
        if (lane < deg) { w = __expf(e0v - m); den += w; }
        sPair[wv][lane] = make_int2(s0, __float_as_int(w));
        int cnt = deg < 64 ? deg : 64;
        phaseC(cnt);
    }
    for (int base = 64; base < deg; base += 64) {
        int j = base + lane;
        int s = 0; float w = 0.f;
        if (j < deg) {
            s = ssrc[beg + j];
            w = __expf(lrelu(asn[s] + adv) - m);
            den += w;
        }
        sPair[wv][lane] = make_int2(s, __float_as_int(w));
        int cnt = deg - base; if (cnt > 64) cnt = 64;
        phaseC(cnt);
    }

    acc += __shfl_xor(acc, 8); acc += __shfl_xor(acc, 16); acc += __shfl_xor(acc, 32);
    #pragma unroll
    for (int off = 32; off; off >>= 1) den += __shfl_xor(den, off);

    float o = acc / (den + 1e-16f) + b2[c];
    float mx = o;
    mx = fmaxf(mx, __shfl_xor(mx, 1));
    mx = fmaxf(mx, __shfl_xor(mx, 2));
    mx = fmaxf(mx, __shfl_xor(mx, 4));
    float ex = __expf(o - mx);
    float sm = ex;
    sm += __shfl_xor(sm, 1); sm += __shfl_xor(sm, 2); sm += __shfl_xor(sm, 4);
    if (g == 0) out[(size_t)node * 8 + c] = o - mx - logf(sm);
}

// ---------------- launch ----------------

extern "C" void kernel_launch(void* const* d_in, const int* in_sizes, int n_in,
                              void* d_out, int out_size, void* d_ws, size_t ws_size,
                              hipStream_t stream) {
    const float* x   = (const float*)d_in[0];
    const int*   ei  = (const int*)d_in[1];
    const float* W0  = (const float*)d_in[2];
    const float* as0 = (const float*)d_in[3];
    const float* ad0 = (const float*)d_in[4];
    const float* b0  = (const float*)d_in[5];
    const float* g0  = (const float*)d_in[6];
    const float* bb0 = (const float*)d_in[7];
    const float* rm0 = (const float*)d_in[8];
    const float* rv0 = (const float*)d_in[9];
    const float* W1  = (const float*)d_in[10];
    const float* as1 = (const float*)d_in[11];
    const float* ad1 = (const float*)d_in[12];
    const float* b1  = (const float*)d_in[13];
    const float* g1  = (const float*)d_in[14];
    const float* bb1 = (const float*)d_in[15];
    const float* rm1 = (const float*)d_in[16];
    const float* rv1 = (const float*)d_in[17];
    const float* W2  = (const float*)d_in[18];
    const float* as2 = (const float*)d_in[19];
    const float* ad2 = (const float*)d_in[20];
    const float* b2  = (const float*)d_in[21];
    float* out = (float*)d_out;

    char* w = (char*)d_ws;
    size_t off = 0;
    auto carve = [&](size_t bytes) {
        void* p = w + off;
        off += (bytes + 255) & ~(size_t)255;
        return p;
    };
    unsigned short* xb   = (unsigned short*)carve((size_t)N_NODES * 128 * 2);
    unsigned short* Hb   = (unsigned short*)carve((size_t)N_NODES * 128 * 2);
    unsigned short* Xb   = (unsigned short*)carve((size_t)N_NODES * 128 * 2);
    unsigned short* W0p  = (unsigned short*)carve(16384 * 2);
    unsigned short* W1p  = (unsigned short*)carve(16384 * 2);
    int*   cnt    = (int*)carve((size_t)N_NODES * 4);
    int*   offs   = (int*)carve((size_t)(N_NODES + 1) * 4);
    int*   cursor = (int*)carve((size_t)N_NODES * 4);
    int*   bsums  = (int*)carve(1024);
    int*   boffs  = (int*)carve(1024);
    int*   ssrc   = (int*)carve((size_t)ET * 4);
    float* asn    = (float*)carve((size_t)N_NODES * 4 * 4);
    float* adn    = (float*)carve((size_t)N_NODES * 4 * 4);
    float* h2     = (float*)carve((size_t)N_NODES * 8 * 4);
    float* as2n   = (float*)carve((size_t)N_NODES * 4);
    float* ad2n   = (float*)carve((size_t)N_NODES * 4);
    (void)ws_size; (void)in_sizes; (void)n_in; (void)out_size;

    const int NB = (N_NODES + 255) / 256;
    const int GB = (N_NODES + 63) / 64;

    hipMemsetAsync(cnt, 0, (size_t)N_NODES * 4, stream);
    count_deg<<<(ET + 255) / 256, 256, 0, stream>>>(ei, cnt);
    scan_partial<<<NB, 256, 0, stream>>>(cnt, offs, bsums);
    scan_root<<<1, 256, 0, stream>>>(bsums, boffs, NB);
    scan_add<<<NB, 256, 0, stream>>>(offs, boffs, bsums, cursor, NB);
    scatter_edges<<<(ET + 255) / 256, 256, 0, stream>>>(ei, cursor, ssrc);

    prep_inputs<<<CAST_B + 2 * PACK_B, 256, 0, stream>>>(x, xb, W0, W0p, W1, W1p);

    gemm_attn<<<GB, 256, 0, stream>>>(xb, W0p, as0, ad0, Hb, asn, adn, N_NODES);
    aggregate<<<(N_NODES + 3) / 4, 256, 0, stream>>>(Hb, asn, adn, offs, ssrc,
                                                     b0, g0, bb0, rm0, rv0, Xb);
    gemm_attn<<<GB, 256, 0, stream>>>(Xb, W1p, as1, ad1, Hb, asn, adn, N_NODES);
    aggregate<<<(N_NODES + 3) / 4, 256, 0, stream>>>(Hb, asn, adn, offs, ssrc,
                                                     b1, g1, bb1, rm1, rv1, Xb);
    gemm2_fused<<<NB, 256, 0, stream>>>(Xb, W2, as2, ad2, h2, as2n, ad2n);
    aggregate2<<<(N_NODES + 3) / 4, 256, 0, stream>>>(h2, as2n, ad2n, offs, ssrc, b2, out);
}

// Round 5
// 365.811 us; speedup vs baseline: 1.6260x; 1.0579x over previous
//
#include <hip/hip_runtime.h>
#include <math.h>

#define N_NODES 50000
#define N_EDGES 800000
#define ET (N_EDGES + N_NODES)   // with self-loops
#define FDIM 128
#define HEADS 4
#define HID 32
#define NCLS 8
#define NEG 0.2f
#define EPS_BN 1e-5f

typedef __attribute__((ext_vector_type(8))) short short8;
typedef __attribute__((ext_vector_type(4))) float f32x4;

__device__ __forceinline__ float lrelu(float e) { return e > 0.f ? e : NEG * e; }
__device__ __forceinline__ float bflo(unsigned u) { return __uint_as_float(u << 16); }
__device__ __forceinline__ float bfhi(unsigned u) { return __uint_as_float(u & 0xffff0000u); }
__device__ __forceinline__ unsigned f2bf(float f) {           // RNE round to bf16 bits
    unsigned b = __float_as_uint(f);
    return (b + 0x7fffu + ((b >> 16) & 1u)) >> 16;
}

// ---------------- graph prep: histogram + scan + scatter ----------------

__global__ void count_deg(const int* __restrict__ ei, int* __restrict__ cnt) {
    int e = blockIdx.x * blockDim.x + threadIdx.x;
    if (e >= ET) return;
    int d = (e < N_EDGES) ? ei[N_EDGES + e] : (e - N_EDGES);
    atomicAdd(&cnt[d], 1);
}

__global__ void scan_partial(const int* __restrict__ cnt, int* __restrict__ offs,
                             int* __restrict__ bsums) {
    __shared__ int s[256];
    int tid = threadIdx.x;
    int i = blockIdx.x * 256 + tid;
    int v = (i < N_NODES) ? cnt[i] : 0;
    s[tid] = v;
    __syncthreads();
    for (int off = 1; off < 256; off <<= 1) {
        int x = (tid >= off) ? s[tid - off] : 0;
        __syncthreads();
        s[tid] += x;
        __syncthreads();
    }
    if (i < N_NODES) offs[i] = s[tid] - v;
    if (tid == 255) bsums[blockIdx.x] = s[255];
}

__global__ void scan_root(const int* __restrict__ bsums, int* __restrict__ boffs, int nb) {
    __shared__ int s[256];
    int tid = threadIdx.x;
    int v = (tid < nb) ? bsums[tid] : 0;
    s[tid] = v;
    __syncthreads();
    for (int off = 1; off < 256; off <<= 1) {
        int x = (tid >= off) ? s[tid - off] : 0;
        __syncthreads();
        s[tid] += x;
        __syncthreads();
    }
    boffs[tid] = s[tid] - v;
}

__global__ void scan_add(int* __restrict__ offs, const int* __restrict__ boffs,
                         const int* __restrict__ bsums, int* __restrict__ cursor, int nb) {
    int i = blockIdx.x * 256 + threadIdx.x;
    if (i < N_NODES) {
        int v = offs[i] + boffs[blockIdx.x];
        offs[i] = v;
        cursor[i] = v;
    }
    if (i == 0) offs[N_NODES] = boffs[nb - 1] + bsums[nb - 1];
}

__global__ void scatter_edges(const int* __restrict__ ei, int* __restrict__ cursor,
                              int* __restrict__ ssrc) {
    int e = blockIdx.x * blockDim.x + threadIdx.x;
    if (e >= ET) return;
    int s, d;
    if (e < N_EDGES) { s = ei[e]; d = ei[N_EDGES + e]; }
    else             { s = d = e - N_EDGES; }
    int pos = atomicAdd(&cursor[d], 1);
    ssrc[pos] = s;
}

// ---------------- fused input prep: x->bf16 cast + W0/W1 fragment packing ----------------

#define CAST_B 3125   // 50000*128/8/256
#define PACK_B 64     // 16384/256

__global__ void prep_inputs(const float* __restrict__ x, unsigned short* __restrict__ xb,
                            const float* __restrict__ W0, unsigned short* __restrict__ W0p,
                            const float* __restrict__ W1, unsigned short* __restrict__ W1p) {
    int b = blockIdx.x, tid = threadIdx.x;
    if (b < CAST_B) {
        int i = b * 256 + tid;
        const float4* p = (const float4*)x + (size_t)i * 2;
        float4 a = p[0], c = p[1];
        uint4 o;
        o.x = f2bf(a.x) | (f2bf(a.y) << 16);
        o.y = f2bf(a.z) | (f2bf(a.w) << 16);
        o.z = f2bf(c.x) | (f2bf(c.y) << 16);
        o.w = f2bf(c.z) | (f2bf(c.w) << 16);
        ((uint4*)xb)[i] = o;
    } else {
        int pb = b - CAST_B;
        const float* W = (pb < PACK_B) ? W0 : W1;
        unsigned short* Wp = (pb < PACK_B) ? W0p : W1p;
        int o = (pb & (PACK_B - 1)) * 256 + tid;
        int j = o & 7, lane = (o >> 3) & 63, kc = (o >> 9) & 3, t = o >> 11;
        int k = kc * 32 + ((lane >> 4) << 3) + j;
        int n = t * 16 + (lane & 15);
        Wp[o] = (unsigned short)f2bf(W[k * 128 + n]);
    }
}

// ------- fused MFMA GEMM (M x 128 @ 128 x 128) + bf16 h-store + attn coeffs -------

__global__ __launch_bounds__(256) void gemm_attn(
        const unsigned short* __restrict__ Ab, const unsigned short* __restrict__ Wp,
        const float* __restrict__ att_s, const float* __restrict__ att_d,
        unsigned short* __restrict__ Hb, float* __restrict__ asn, float* __restrict__ adn,
        int M) {
    __shared__ float tiles[64 * 132];
    int tid = threadIdx.x;
    int wv = tid >> 6, lane = tid & 63;
    int base = blockIdx.x * 64;
    int mrow = base + wv * 16 + (lane & 15);
    if (mrow >= M) mrow = M - 1;
    int koff = (lane >> 4) * 8;

    f32x4 acc[8];
    #pragma unroll
    for (int t = 0; t < 8; t++) acc[t] = (f32x4){0.f, 0.f, 0.f, 0.f};

    #pragma unroll
    for (int kc = 0; kc < 4; kc++) {
        short8 a = *(const short8*)(Ab + (size_t)mrow * 128 + kc * 32 + koff);
        #pragma unroll
        for (int t = 0; t < 8; t++) {
            short8 b = *(const short8*)(Wp + (((t * 4 + kc) * 64 + lane) << 3));
            acc[t] = __builtin_amdgcn_mfma_f32_16x16x32_bf16(a, b, acc[t], 0, 0, 0);
        }
    }

    int rbase = wv * 16 + (lane >> 4) * 4;
    int col = lane & 15;
    #pragma unroll
    for (int t = 0; t < 8; t++)
        #pragma unroll
        for (int r = 0; r < 4; r++)
            tiles[(rbase + r) * 132 + t * 16 + col] = acc[t][r];
    __syncthreads();

    #pragma unroll
    for (int it = 0; it < 4; it++) {
        int u = tid + it * 256;
        int rl = u >> 4, cg = u & 15;
        int row = base + rl;
        if (row < M) {
            const float* p = tiles + rl * 132 + cg * 8;
            float4 v0 = *(const float4*)(p);
            float4 v1 = *(const float4*)(p + 4);
            uint4 o;
            o.x = f2bf(v0.x) | (f2bf(v0.y) << 16);
            o.y = f2bf(v0.z) | (f2bf(v0.w) << 16);
            o.z = f2bf(v1.x) | (f2bf(v1.y) << 16);
            o.w = f2bf(v1.z) | (f2bf(v1.w) << 16);
            *(uint4*)(Hb + (size_t)row * 128 + cg * 8) = o;
        }
    }

    {
        int rl = tid >> 2, hd = tid & 3;
        int row = base + rl;
        if (row < M) {
            const float* hrow = tiles + rl * 132 + hd * 32;
            const float* as = att_s + hd * 32;
            const float* ad = att_d + hd * 32;
            float ps = 0.f, pd = 0.f;
            #pragma unroll
            for (int i = 0; i < 8; i++) {
                float4 hv = *(const float4*)(hrow + i * 4);
                float4 sv = *(const float4*)(as + i * 4);
                float4 dv = *(const float4*)(ad + i * 4);
                ps += hv.x * sv.x + hv.y * sv.y + hv.z * sv.z + hv.w * sv.w;
                pd += hv.x * dv.x + hv.y * dv.y + hv.z * dv.z + hv.w * dv.w;
            }
            asn[row * 4 + hd] = ps;
            adn[row * 4 + hd] = pd;
        }
    }
}

// ------- aggregation + bias + BN + ELU (layers 0,1): one wave/node, channel-parallel -------
// lane owns channels {2*lane, 2*lane+1}; head = lane>>4. Phase C: per edge the wave
// reads one coalesced 256 B bf16 row; 4-edge unroll; no accumulator reduction needed.

__global__ __launch_bounds__(256) void aggregate(
        const unsigned short* __restrict__ hb, const float* __restrict__ asn,
        const float* __restrict__ adn, const int* __restrict__ offs,
        const int* __restrict__ ssrc, const float* __restrict__ bias,
        const float* __restrict__ gamma, const float* __restrict__ beta,
        const float* __restrict__ rmean, const float* __restrict__ rvar,
        unsigned short* __restrict__ outb) {
    __shared__ int2 sPair[4][4][68];   // [wave][head][slot]; stride 68 -> heads 8 banks apart
    int wv = threadIdx.x >> 6;
    int node = blockIdx.x * 4 + wv;
    if (node >= N_NODES) return;
    int lane = threadIdx.x & 63;
    int hd = lane >> 4;
    int beg = offs[node], deg = offs[node + 1] - beg;
    float4 ad4 = *(const float4*)(adn + node * 4);

    // zero pad slots 64..67 (for unroll-4 overrun; w=0 -> harmless)
    if (lane < 16) sPair[wv][lane >> 2][64 + (lane & 3)] = make_int2(0, 0);

    // sweep 1: edge-parallel per-head max; block-0 edges cached in registers
    int s0 = 0;
    float4 e4 = make_float4(-1e30f, -1e30f, -1e30f, -1e30f);
    if (lane < deg) {
        s0 = ssrc[beg + lane];
        float4 a = *(const float4*)(asn + s0 * 4);
        e4.x = lrelu(a.x + ad4.x); e4.y = lrelu(a.y + ad4.y);
        e4.z = lrelu(a.z + ad4.z); e4.w = lrelu(a.w + ad4.w);
    }
    float4 m4 = e4;
    for (int base = 64; base < deg; base += 64) {   // rare
        int j = base + lane;
        if (j < deg) {
            int s = ssrc[beg + j];
            float4 a = *(const float4*)(asn + s * 4);
            m4.x = fmaxf(m4.x, lrelu(a.x + ad4.x));
            m4.y = fmaxf(m4.y, lrelu(a.y + ad4.y));
            m4.z = fmaxf(m4.z, lrelu(a.z + ad4.z));
            m4.w = fmaxf(m4.w, lrelu(a.w + ad4.w));
        }
    }
    #pragma unroll
    for (int off = 32; off; off >>= 1) {
        m4.x = fmaxf(m4.x, __shfl_xor(m4.x, off));
        m4.y = fmaxf(m4.y, __shfl_xor(m4.y, off));
        m4.z = fmaxf(m4.z, __shfl_xor(m4.z, off));
        m4.w = fmaxf(m4.w, __shfl_xor(m4.w, off));
    }

    float4 den4 = make_float4(0.f, 0.f, 0.f, 0.f);
    float acc0 = 0.f, acc1 = 0.f;
    const unsigned short* hlane = hb + 2 * lane;
    const int2* pp = &sPair[wv][hd][0];

    auto phaseC = [&](int cnt) {
        int bound = (cnt + 3) & ~3;
        for (int i = 0; i < bound; i += 4) {
            int2 p0 = pp[i], p1 = pp[i + 1], p2 = pp[i + 2], p3 = pp[i + 3];
            unsigned u0 = *(const unsigned*)(hlane + (((unsigned)p0.x) << 7));
            unsigned u1 = *(const unsigned*)(hlane + (((unsigned)p1.x) << 7));
            unsigned u2 = *(const unsigned*)(hlane + (((unsigned)p2.x) << 7));
            unsigned u3 = *(const unsigned*)(hlane + (((unsigned)p3.x) << 7));
            float w0 = __int_as_float(p0.y), w1 = __int_as_float(p1.y);
            float w2 = __int_as_float(p2.y), w3 = __int_as_float(p3.y);
            acc0 += w0 * bflo(u0); acc1 += w0 * bfhi(u0);
            acc0 += w1 * bflo(u1); acc1 += w1 * bfhi(u1);
            acc0 += w2 * bflo(u2); acc1 += w2 * bfhi(u2);
            acc0 += w3 * bflo(u3); acc1 += w3 * bfhi(u3);
        }
    };

    // block 0: weights from registers
    {
        float4 w4 = make_float4(0.f, 0.f, 0.f, 0.f);
        if (lane < deg) {
            w4.x = __expf(e4.x - m4.x); w4.y = __expf(e4.y - m4.y);
            w4.z = __expf(e4.z - m4.z); w4.w = __expf(e4.w - m4.w);
            den4.x += w4.x; den4.y += w4.y; den4.z += w4.z; den4.w += w4.w;
        }
        sPair[wv][0][lane] = make_int2(s0, __float_as_int(w4.x));
        sPair[wv][1][lane] = make_int2(s0, __float_as_int(w4.y));
        sPair[wv][2][lane] = make_int2(s0, __float_as_int(w4.z));
        sPair[wv][3][lane] = make_int2(s0, __float_as_int(w4.w));
        phaseC(deg < 64 ? deg : 64);
    }
    // rare extra blocks
    for (int base = 64; base < deg; base += 64) {
        int j = base + lane;
        int s = 0;
        float4 w4 = make_float4(0.f, 0.f, 0.f, 0.f);
        if (j < deg) {
            s = ssrc[beg + j];
            float4 a = *(const float4*)(asn + s * 4);
            w4.x = __expf(lrelu(a.x + ad4.x) - m4.x);
            w4.y = __expf(lrelu(a.y + ad4.y) - m4.y);
            w4.z = __expf(lrelu(a.z + ad4.z) - m4.z);
            w4.w = __expf(lrelu(a.w + ad4.w) - m4.w);
            den4.x += w4.x; den4.y += w4.y; den4.z += w4.z; den4.w += w4.w;
        }
        sPair[wv][0][lane] = make_int2(s, __float_as_int(w4.x));
        sPair[wv][1][lane] = make_int2(s, __float_as_int(w4.y));
        sPair[wv][2][lane] = make_int2(s, __float_as_int(w4.z));
        sPair[wv][3][lane] = make_int2(s, __float_as_int(w4.w));
        int cnt = deg - base; if (cnt > 64) cnt = 64;
        phaseC(cnt);
    }

    #pragma unroll
    for (int off = 32; off; off >>= 1) {
        den4.x += __shfl_xor(den4.x, off);
        den4.y += __shfl_xor(den4.y, off);
        den4.z += __shfl_xor(den4.z, off);
        den4.w += __shfl_xor(den4.w, off);
    }
    float den = (hd & 2) ? ((hd & 1) ? den4.w : den4.z)
                         : ((hd & 1) ? den4.y : den4.x);
    float inv = 1.f / (den + 1e-16f);

    int c0 = lane * 2;
    float2 bi = *(const float2*)(bias + c0);
    float2 gm = *(const float2*)(gamma + c0);
    float2 bt = *(const float2*)(beta + c0);
    float2 rm = *(const float2*)(rmean + c0);
    float2 rv = *(const float2*)(rvar + c0);
    float o0 = acc0 * inv + bi.x;
    float o1 = acc1 * inv + bi.y;
    o0 = (o0 - rm.x) * rsqrtf(rv.x + EPS_BN) * gm.x + bt.x;
    o1 = (o1 - rm.y) * rsqrtf(rv.y + EPS_BN) * gm.y + bt.y;
    o0 = (o0 > 0.f) ? o0 : expm1f(o0);
    o1 = (o1 > 0.f) ? o1 : expm1f(o1);
    *(unsigned*)(outb + (size_t)node * 128 + c0) = f2bf(o0) | (f2bf(o1) << 16);
}

// ---------------- layer 2: fused GEMM(128->8) + attn coeffs (bf16 input) ----------------

__global__ __launch_bounds__(256) void gemm2_fused(
        const unsigned short* __restrict__ xb, const float* __restrict__ W2,
        const float* __restrict__ as2, const float* __restrict__ ad2,
        float* __restrict__ h2, float* __restrict__ asn, float* __restrict__ adn) {
    __shared__ float sW[128 * 8];
    __shared__ float sas[8], sad[8];
    int tid = threadIdx.x;
    for (int i = tid; i < 1024; i += 256) sW[i] = W2[i];
    if (tid < 8) { sas[tid] = as2[tid]; sad[tid] = ad2[tid]; }
    __syncthreads();
    int node = blockIdx.x * 256 + tid;
    if (node >= N_NODES) return;
    const uint4* xr = (const uint4*)(xb + (size_t)node * 128);
    float acc[8];
    #pragma unroll
    for (int c = 0; c < 8; c++) acc[c] = 0.f;
    for (int k8 = 0; k8 < 16; k8++) {
        uint4 u = xr[k8];
        float f[8] = { bflo(u.x), bfhi(u.x), bflo(u.y), bfhi(u.y),
                       bflo(u.z), bfhi(u.z), bflo(u.w), bfhi(u.w) };
        int kb = k8 * 8;
        #pragma unroll
        for (int q = 0; q < 8; q++)
            #pragma unroll
            for (int c = 0; c < 8; c++)
                acc[c] += f[q] * sW[(kb + q) * 8 + c];
    }
    float ps = 0.f, pd = 0.f;
    #pragma unroll
    for (int c = 0; c < 8; c++) {
        h2[(size_t)node * 8 + c] = acc[c];
        ps += acc[c] * sas[c];
        pd += acc[c] * sad[c];
    }
    asn[node] = ps;
    adn[node] = pd;
}

// ------- layer 2 aggregation + bias + log_softmax: one wave/node -------

__global__ __launch_bounds__(256) void aggregate2(
        const float* __restrict__ h2, const float* __restrict__ asn,
        const float* __restrict__ adn, const int* __restrict__ offs,
        const int* __restrict__ ssrc, const float* __restrict__ b2,
        float* __restrict__ out) {
    __shared__ int2 sPair[4][64];
    int wv = threadIdx.x >> 6;
    int node = blockIdx.x * 4 + wv;
    if (node >= N_NODES) return;
    int lane = threadIdx.x & 63;
    int g = lane >> 3, c = lane & 7;   // 8 edge groups x 8 channels
    int beg = offs[node], end = offs[node + 1];
    int deg = end - beg;
    float adv = adn[node];

    int s0 = 0;
    float e0v = -1e30f;
    if (lane < deg) {
        s0 = ssrc[beg + lane];
        e0v = lrelu(asn[s0] + adv);
    }
    float m = e0v;
    for (int base = 64; base < deg; base += 64) {
        int j = base + lane;
        if (j < deg) m = fmaxf(m, lrelu(asn[ssrc[beg + j]] + adv));
    }
    #pragma unroll
    for (int off = 32; off; off >>= 1) m = fmaxf(m, __shfl_xor(m, off));

    float den = 0.f, acc = 0.f;
    auto phaseC = [&](int cnt) {
        int nIt = (cnt + 15) >> 4;
        const int2* pp = &sPair[wv][0];
        for (int i = 0; i < nIt; i++) {
            int e = i * 16 + g;
            int2 p0 = pp[e];
            int2 p1 = pp[e + 8];
            acc += __int_as_float(p0.y) * h2[(((unsigned)p0.x) << 3) + c];
            acc += __int_as_float(p1.y) * h2[(((unsigned)p1.x) << 3) + c];
        }
    };

    {
        float w = 0.f;
        if (lane < deg) { w = __expf(e0v - m); den += w; }
        sPair[wv][lane] = make_int2(s0, __float_as_int(w));
        int cnt = deg < 64 ? deg : 64;
        phaseC(cnt);
    }
    for (int base = 64; base < deg; base += 64) {
        int j = base + lane;
        int s = 0; float w = 0.f;
        if (j < deg) {
            s = ssrc[beg + j];
            w = __expf(lrelu(asn[s] + adv) - m);
            den += w;
        }
        sPair[wv][lane] = make_int2(s, __float_as_int(w));
        int cnt = deg - base; if (cnt > 64) cnt = 64;
        phaseC(cnt);
    }

    acc += __shfl_xor(acc, 8); acc += __shfl_xor(acc, 16); acc += __shfl_xor(acc, 32);
    #pragma unroll
    for (int off = 32; off; off >>= 1) den += __shfl_xor(den, off);

    float o = acc / (den + 1e-16f) + b2[c];
    float mx = o;
    mx = fmaxf(mx, __shfl_xor(mx, 1));
    mx = fmaxf(mx, __shfl_xor(mx, 2));
    mx = fmaxf(mx, __shfl_xor(mx, 4));
    float ex = __expf(o - mx);
    float sm = ex;
    sm += __shfl_xor(sm, 1); sm += __shfl_xor(sm, 2); sm += __shfl_xor(sm, 4);
    if (g == 0) out[(size_t)node * 8 + c] = o - mx - logf(sm);
}

// ---------------- launch ----------------

extern "C" void kernel_launch(void* const* d_in, const int* in_sizes, int n_in,
                              void* d_out, int out_size, void* d_ws, size_t ws_size,
                              hipStream_t stream) {
    const float* x   = (const float*)d_in[0];
    const int*   ei  = (const int*)d_in[1];
    const float* W0  = (const float*)d_in[2];
    const float* as0 = (const float*)d_in[3];
    const float* ad0 = (const float*)d_in[4];
    const float* b0  = (const float*)d_in[5];
    const float* g0  = (const float*)d_in[6];
    const float* bb0 = (const float*)d_in[7];
    const float* rm0 = (const float*)d_in[8];
    const float* rv0 = (const float*)d_in[9];
    const float* W1  = (const float*)d_in[10];
    const float* as1 = (const float*)d_in[11];
    const float* ad1 = (const float*)d_in[12];
    const float* b1  = (const float*)d_in[13];
    const float* g1  = (const float*)d_in[14];
    const float* bb1 = (const float*)d_in[15];
    const float* rm1 = (const float*)d_in[16];
    const float* rv1 = (const float*)d_in[17];
    const float* W2  = (const float*)d_in[18];
    const float* as2 = (const float*)d_in[19];
    const float* ad2 = (const float*)d_in[20];
    const float* b2  = (const float*)d_in[21];
    float* out = (float*)d_out;

    char* w = (char*)d_ws;
    size_t off = 0;
    auto carve = [&](size_t bytes) {
        void* p = w + off;
        off += (bytes + 255) & ~(size_t)255;
        return p;
    };
    unsigned short* xb   = (unsigned short*)carve((size_t)N_NODES * 128 * 2);
    unsigned short* Hb   = (unsigned short*)carve((size_t)N_NODES * 128 * 2);
    unsigned short* Xb   = (unsigned short*)carve((size_t)N_NODES * 128 * 2);
    unsigned short* W0p  = (unsigned short*)carve(16384 * 2);
    unsigned short* W1p  = (unsigned short*)carve(16384 * 2);
    int*   cnt    = (int*)carve((size_t)N_NODES * 4);
    int*   offs   = (int*)carve((size_t)(N_NODES + 1) * 4);
    int*   cursor = (int*)carve((size_t)N_NODES * 4);
    int*   bsums  = (int*)carve(1024);
    int*   boffs  = (int*)carve(1024);
    int*   ssrc   = (int*)carve((size_t)ET * 4);
    float* asn    = (float*)carve((size_t)N_NODES * 4 * 4);
    float* adn    = (float*)carve((size_t)N_NODES * 4 * 4);
    float* h2     = (float*)carve((size_t)N_NODES * 8 * 4);
    float* as2n   = (float*)carve((size_t)N_NODES * 4);
    float* ad2n   = (float*)carve((size_t)N_NODES * 4);
    (void)ws_size; (void)in_sizes; (void)n_in; (void)out_size;

    const int NB = (N_NODES + 255) / 256;
    const int GB = (N_NODES + 63) / 64;

    hipMemsetAsync(cnt, 0, (size_t)N_NODES * 4, stream);
    count_deg<<<(ET + 255) / 256, 256, 0, stream>>>(ei, cnt);
    scan_partial<<<NB, 256, 0, stream>>>(cnt, offs, bsums);
    scan_root<<<1, 256, 0, stream>>>(bsums, boffs, NB);
    scan_add<<<NB, 256, 0, stream>>>(offs, boffs, bsums, cursor, NB);
    scatter_edges<<<(ET + 255) / 256, 256, 0, stream>>>(ei, cursor, ssrc);

    prep_inputs<<<CAST_B + 2 * PACK_B, 256, 0, stream>>>(x, xb, W0, W0p, W1, W1p);

    gemm_attn<<<GB, 256, 0, stream>>>(xb, W0p, as0, ad0, Hb, asn, adn, N_NODES);
    aggregate<<<(N_NODES + 3) / 4, 256, 0, stream>>>(Hb, asn, adn, offs, ssrc,
                                                     b0, g0, bb0, rm0, rv0, Xb);
    gemm_attn<<<GB, 256, 0, stream>>>(Xb, W1p, as1, ad1, Hb, asn, adn, N_NODES);
    aggregate<<<(N_NODES + 3) / 4, 256, 0, stream>>>(Hb, asn, adn, offs, ssrc,
                                                     b1, g1, bb1, rm1, rv1, Xb);
    gemm2_fused<<<NB, 256, 0, stream>>>(Xb, W2, as2, ad2, h2, as2n, ad2n);
    aggregate2<<<(N_NODES + 3) / 4, 256, 0, stream>>>(h2, as2n, ad2n, offs, ssrc, b2, out);
}